// Round 2
// baseline (506.097 us; speedup 1.0000x reference)
//
#include <hip/hip_runtime.h>

// ---------------- problem dims ----------------
#define NB   16
#define TT   2000
#define TP   2048      // padded T for GEMM tiling
#define ENC  512
#define ATTD 512
#define HH   4
#define CC   10
#define KK   64        // conv half-window
#define KW   129       // 2K+1
#define HATT 2048

typedef unsigned short u16;
typedef __attribute__((ext_vector_type(8))) short bf16x8;
typedef __attribute__((ext_vector_type(4))) float f32x4;

// round-to-nearest-even f32 -> bf16, packed pair
__device__ inline unsigned bfpack2(float lo, float hi) {
    unsigned a = __builtin_bit_cast(unsigned, lo);
    unsigned b = __builtin_bit_cast(unsigned, hi);
    a = (a + 0x7fffu + ((a >> 16) & 1u)) >> 16;
    b = (b + 0x7fffu + ((b >> 16) & 1u)) >> 16;
    return a | (b << 16);
}

__device__ inline float ftanh(float x) {
    float xc = fminf(fmaxf(x, -15.f), 15.f);
    float e = __expf(2.f * xc);
    return (e - 1.f) / (e + 1.f);
}

// ---------------- 1. convert enc_pad & Wk to bf16 (A zero-padded to TP rows) ----
__global__ __launch_bounds__(256) void convert_kernel(
    const float* __restrict__ enc, const float* __restrict__ Wk,
    u16* __restrict__ Abf, u16* __restrict__ Wkbf)
{
    long long gid = ((long long)blockIdx.x * 256 + threadIdx.x) * 8;
    const long long ATOT = (long long)NB * TP * ENC;   // 1<<24
    if (gid < ATOT) {
        int n = (int)(gid >> 20);
        int rem = (int)(gid & ((1 << 20) - 1));
        int r = rem >> 9, e = rem & 511;
        uint4 out;
        if (r < TT) {
            const float* s = enc + ((long long)n * TT + r) * ENC + e;
            float4 v0 = *(const float4*)s;
            float4 v1 = *(const float4*)(s + 4);
            out.x = bfpack2(v0.x, v0.y); out.y = bfpack2(v0.z, v0.w);
            out.z = bfpack2(v1.x, v1.y); out.w = bfpack2(v1.z, v1.w);
        } else {
            out.x = out.y = out.z = out.w = 0u;
        }
        *(uint4*)(Abf + gid) = out;
    } else {
        long long j = gid - ATOT;                       // < 2048*512
        const float* s = Wk + j;
        float4 v0 = *(const float4*)s;
        float4 v1 = *(const float4*)(s + 4);
        uint4 out;
        out.x = bfpack2(v0.x, v0.y); out.y = bfpack2(v0.z, v0.w);
        out.z = bfpack2(v1.x, v1.y); out.w = bfpack2(v1.z, v1.w);
        *(uint4*)(Wkbf + j) = out;
    }
}

// ---------------- 2. location features f[n][h][c][t] (grouped conv1d) ----------
__global__ __launch_bounds__(256) void conv_f_kernel(
    const float* __restrict__ ali_prev, const float* __restrict__ WF,
    const float* __restrict__ bF, float* __restrict__ f)
{
    int bid = blockIdx.x;          // n*16 + h*4 + tc
    int tc = bid & 3, h = (bid >> 2) & 3, n = bid >> 4;
    int t0 = tc * 500;
    __shared__ float aliW[628];    // window [t0-64, t0+564)
    __shared__ float wf[CC][KW];
    __shared__ float bfs[CC];
    const float* arow = ali_prev + ((long long)n * HH + h) * TT;
    for (int i = threadIdx.x; i < 628; i += 256) {
        int tt = t0 - KK + i;
        aliW[i] = (tt >= 0 && tt < TT) ? arow[tt] : 0.f;
    }
    for (int i = threadIdx.x; i < CC * KW; i += 256) {
        int c = i / KW, k = i - c * KW;
        wf[c][k] = WF[(h * CC + c) * KW + k];
    }
    if (threadIdx.x < CC) bfs[threadIdx.x] = bF[h * CC + threadIdx.x];
    __syncthreads();
    for (int idx = threadIdx.x; idx < CC * 500; idx += 256) {
        int c = idx / 500, tl = idx - c * 500;
        float acc = bfs[c];
        for (int k = 0; k < KW; k++) acc += aliW[tl + k] * wf[c][k];
        f[(((long long)n * HH + h) * CC + c) * TT + t0 + tl] = acc;
    }
}

// ---------------- 3. dec_part[n][2048] = dec_prev @ Wd^T -----------------------
__global__ __launch_bounds__(256) void dec_part_kernel(
    const float* __restrict__ dec_prev, const float* __restrict__ Wd,
    float* __restrict__ dec_part)
{
    __shared__ float dp[NB * 512];
    for (int i = threadIdx.x; i < NB * 512; i += 256) dp[i] = dec_prev[i];
    __syncthreads();
    int d = blockIdx.x * 256 + threadIdx.x;  // 0..2047
    float acc[NB];
    for (int n = 0; n < NB; n++) acc[n] = 0.f;
    const float4* w4 = (const float4*)(Wd + (long long)d * 512);
    for (int e4 = 0; e4 < 128; e4++) {
        float4 w = w4[e4];
        #pragma unroll
        for (int n = 0; n < NB; n++) {
            const float* dpn = dp + n * 512 + e4 * 4;
            acc[n] += w.x * dpn[0] + w.y * dpn[1] + w.z * dpn[2] + w.w * dpn[3];
        }
    }
    for (int n = 0; n < NB; n++) dec_part[n * HATT + d] = acc[n];
}

// ---------------- 4. big fused GEMM: kp + tanh-score reduction -----------------
// grid (nt=16, mt=16, n=16); block 256 (4 waves, each 64x64 of the 128x128 tile)
__global__ __launch_bounds__(256) void score_gemm_kernel(
    const u16* __restrict__ Abf, const u16* __restrict__ Bbf,
    const float* __restrict__ fbuf, const float* __restrict__ dec_part,
    const float* __restrict__ Wa, const float* __restrict__ Ww,
    float* __restrict__ score_part)
{
    __shared__ __attribute__((aligned(16))) u16 lA[128 * 64];
    __shared__ __attribute__((aligned(16))) u16 lB[128 * 64];
    __shared__ float fT[CC * 128];
    __shared__ float waS[128 * CC];
    __shared__ float wwS[128];
    __shared__ float decS[128];
    __shared__ float sred[2][128];   // [col-half][row] cross-wave score combine

    const int n = blockIdx.z, mt = blockIdx.y, nt = blockIdx.x;
    const int tid = threadIdx.x, wave = tid >> 6, lane = tid & 63;
    const int l16 = lane & 15, lk = lane >> 4;
    const int h = nt >> 2;

    const u16* Aptr = Abf + ((long long)n * TP + mt * 128) * ENC;
    const u16* Bptr = Bbf + (long long)nt * 128 * ENC;

    f32x4 acc[4][4];
    #pragma unroll
    for (int mi = 0; mi < 4; mi++)
        #pragma unroll
        for (int nj = 0; nj < 4; nj++) {
            f32x4 z = {0.f, 0.f, 0.f, 0.f};
            acc[mi][nj] = z;
        }

    const int wrow = (wave >> 1) * 64, wcol = (wave & 1) * 64;

    for (int k0 = 0; k0 < ENC; k0 += 64) {
        // stage 128x64 bf16 tiles; linear LDS, wave-uniform dest base + lane*16
        #pragma unroll
        for (int i = 0; i < 4; i++) {
            int b = i * 4096 + tid * 16;       // byte index in tile
            int r = b >> 7, kb = b & 127;      // row, byte-in-row
            __builtin_amdgcn_global_load_lds(
                (const __attribute__((address_space(1))) void*)(Aptr + r * ENC + k0 + (kb >> 1)),
                (__attribute__((address_space(3))) void*)((char*)lA + i * 4096 + wave * 1024),
                16, 0, 0);
            __builtin_amdgcn_global_load_lds(
                (const __attribute__((address_space(1))) void*)(Bptr + r * ENC + k0 + (kb >> 1)),
                (__attribute__((address_space(3))) void*)((char*)lB + i * 4096 + wave * 1024),
                16, 0, 0);
        }
        __syncthreads();
        #pragma unroll
        for (int ks = 0; ks < 64; ks += 32) {
            bf16x8 af[4], bf[4];
            #pragma unroll
            for (int mi = 0; mi < 4; mi++)
                af[mi] = *(const bf16x8*)(lA + (wrow + mi * 16 + l16) * 64 + ks + lk * 8);
            #pragma unroll
            for (int nj = 0; nj < 4; nj++)
                bf[nj] = *(const bf16x8*)(lB + (wcol + nj * 16 + l16) * 64 + ks + lk * 8);
            #pragma unroll
            for (int mi = 0; mi < 4; mi++)
                #pragma unroll
                for (int nj = 0; nj < 4; nj++)
                    acc[mi][nj] = __builtin_amdgcn_mfma_f32_16x16x32_bf16(
                        af[mi], bf[nj], acc[mi][nj], 0, 0, 0);
        }
        __syncthreads();
    }

    // ---- epilogue: score_part[q][n][h][t] = sum_{d in col chunk} Ww*tanh(kp+att+dec)
    const int t0 = mt * 128, dd0 = (nt & 3) * 128;
    for (int i = tid; i < CC * 128; i += 256) {
        int c = i >> 7, r = i & 127;
        int t = t0 + r;
        fT[c * 128 + r] = (t < TT) ? fbuf[(((long long)n * HH + h) * CC + c) * TT + t] : 0.f;
    }
    for (int i = tid; i < 128 * CC; i += 256) {
        int col = i / CC, c = i - col * CC;
        waS[i] = Wa[((long long)h * ATTD + dd0 + col) * CC + c];
    }
    if (tid < 128) {
        wwS[tid] = Ww[h * ATTD + dd0 + tid];
        decS[tid] = dec_part[n * HATT + nt * 128 + tid];
    }
    __syncthreads();

    // each wave reduces its 64-column half for its 64 rows into sred[colhalf][row]
    #pragma unroll
    for (int mi = 0; mi < 4; mi++) {
        #pragma unroll
        for (int j = 0; j < 4; j++) {
            int rl = wrow + mi * 16 + lk * 4 + j;
            float s = 0.f;
            #pragma unroll
            for (int nj = 0; nj < 4; nj++) {
                int cl = wcol + nj * 16 + l16;
                float v = acc[mi][nj][j] + decS[cl];
                const float* wac = waS + cl * CC;
                float att = 0.f;
                #pragma unroll
                for (int c = 0; c < CC; c++) att += wac[c] * fT[c * 128 + rl];
                v += att;
                s += wwS[cl] * ftanh(v);
            }
            s += __shfl_xor(s, 1); s += __shfl_xor(s, 2);
            s += __shfl_xor(s, 4); s += __shfl_xor(s, 8);
            if (l16 == 0) sred[wave & 1][rl] = s;
        }
    }
    __syncthreads();
    if (tid < 128) {
        int t = t0 + tid;
        if (t < TT)
            score_part[((long long)((nt & 3) * NB + n) * HH + h) * TT + t] =
                sred[0][tid] + sred[1][tid];
    }
}

// ---------------- 5. masked softmax over t (sums the 4 partial slices) ---------
__global__ __launch_bounds__(256) void softmax_kernel(
    const float* __restrict__ score_part, const int* __restrict__ enc_len,
    float* __restrict__ ali)
{
    int n = blockIdx.x >> 2, h = blockIdx.x & 3;
    int len = enc_len[n];
    int tid = threadIdx.x;
    float s[8];
    float lmax = -3.4e38f;
    #pragma unroll
    for (int i = 0; i < 8; i++) {
        int t = tid + i * 256;
        float v = -3.4e38f;
        if (t < len) {
            v = 0.f;
            #pragma unroll
            for (int q = 0; q < 4; q++)
                v += score_part[((long long)(q * NB + n) * HH + h) * TT + t];
        }
        s[i] = v;
        lmax = fmaxf(lmax, v);
    }
    __shared__ float red[256];
    red[tid] = lmax; __syncthreads();
    for (int off = 128; off; off >>= 1) {
        if (tid < off) red[tid] = fmaxf(red[tid], red[tid + off]);
        __syncthreads();
    }
    float bmax = red[0];
    __syncthreads();
    float lsum = 0.f;
    #pragma unroll
    for (int i = 0; i < 8; i++) {
        int t = tid + i * 256;
        if (t < len) { s[i] = expf(s[i] - bmax); lsum += s[i]; }
        else s[i] = 0.f;
    }
    red[tid] = lsum; __syncthreads();
    for (int off = 128; off; off >>= 1) {
        if (tid < off) red[tid] += red[tid + off];
        __syncthreads();
    }
    float inv = 1.f / red[0];
    float* arow = ali + ((long long)n * HH + h) * TT;
    #pragma unroll
    for (int i = 0; i < 8; i++) {
        int t = tid + i * 256;
        if (t < TT) arow[t] = s[i] * inv;
    }
}

// ---------------- 6. a_enc partials: alignment-weighted encoder average --------
// grid = n(16) x tchunk(16); thread covers 2 enc dims; deterministic partials
__global__ __launch_bounds__(256) void a_enc_kernel(
    const float* __restrict__ ali, const float* __restrict__ enc_pad,
    float* __restrict__ a_enc_part)
{
    int tc = blockIdx.x & 15, n = blockIdx.x >> 4;
    int tid = threadIdx.x;
    float acc[HH][2];
    #pragma unroll
    for (int hh = 0; hh < HH; hh++) { acc[hh][0] = 0.f; acc[hh][1] = 0.f; }
    for (int tt = 0; tt < 125; tt++) {
        int t = tc * 125 + tt;
        float w0 = ali[((long long)n * HH + 0) * TT + t];
        float w1 = ali[((long long)n * HH + 1) * TT + t];
        float w2 = ali[((long long)n * HH + 2) * TT + t];
        float w3 = ali[((long long)n * HH + 3) * TT + t];
        float2 ev = *(const float2*)(enc_pad + ((long long)n * TT + t) * ENC + tid * 2);
        acc[0][0] += w0 * ev.x; acc[0][1] += w0 * ev.y;
        acc[1][0] += w1 * ev.x; acc[1][1] += w1 * ev.y;
        acc[2][0] += w2 * ev.x; acc[2][1] += w2 * ev.y;
        acc[3][0] += w3 * ev.x; acc[3][1] += w3 * ev.y;
    }
    #pragma unroll
    for (int hh = 0; hh < HH; hh++) {
        a_enc_part[(((long long)tc * NB + n) * HH + hh) * ENC + tid * 2 + 0] = acc[hh][0];
        a_enc_part[(((long long)tc * NB + n) * HH + hh) * ENC + tid * 2 + 1] = acc[hh][1];
    }
}

// ---------------- 7. ctx_tmp[n][j] = a_enc[n,h,:] @ We[j,:] + be[j] ------------
__global__ __launch_bounds__(256) void ctx_tmp_kernel(
    const float* __restrict__ a_enc_part, const float* __restrict__ We,
    const float* __restrict__ be, float* __restrict__ ctx_tmp)
{
    int j = blockIdx.x * 256 + threadIdx.x;   // 0..2047 (h uniform per block)
    int h = j >> 9;
    __shared__ float ae[NB * 512];
    for (int i = threadIdx.x; i < NB * 512; i += 256) {
        int nn = i >> 9, e = i & 511;
        float sum = 0.f;
        for (int tc = 0; tc < 16; tc++)
            sum += a_enc_part[(((long long)tc * NB + nn) * HH + h) * ENC + e];
        ae[i] = sum;
    }
    __syncthreads();
    float acc[NB];
    for (int n = 0; n < NB; n++) acc[n] = 0.f;
    const float4* w4 = (const float4*)(We + (long long)j * 512);
    for (int e4 = 0; e4 < 128; e4++) {
        float4 w = w4[e4];
        #pragma unroll
        for (int n = 0; n < NB; n++) {
            const float* a = ae + n * 512 + e4 * 4;
            acc[n] += w.x * a[0] + w.y * a[1] + w.z * a[2] + w.w * a[3];
        }
    }
    float bias = be[j];
    for (int n = 0; n < NB; n++) ctx_tmp[n * HATT + j] = acc[n] + bias;
}

// ---------------- 8. ctx_out[n][e] = ctx_tmp[n,:] @ Wc[e,:] + bc[e] ------------
__global__ __launch_bounds__(256) void ctx_out_kernel(
    const float* __restrict__ ctx_tmp, const float* __restrict__ Wc,
    const float* __restrict__ bc, float* __restrict__ out_ctx)
{
    int eo = blockIdx.x * 256 + threadIdx.x;  // 0..511
    __shared__ float ct[NB * 512];
    float acc[NB];
    for (int n = 0; n < NB; n++) acc[n] = 0.f;
    for (int jc = 0; jc < 4; jc++) {
        for (int i = threadIdx.x; i < NB * 512; i += 256) {
            int nn = i >> 9, jj = i & 511;
            ct[i] = ctx_tmp[nn * HATT + jc * 512 + jj];
        }
        __syncthreads();
        const float4* w4 = (const float4*)(Wc + (long long)eo * HATT + jc * 512);
        for (int j4 = 0; j4 < 128; j4++) {
            float4 w = w4[j4];
            #pragma unroll
            for (int n = 0; n < NB; n++) {
                const float* a = ct + n * 512 + j4 * 4;
                acc[n] += w.x * a[0] + w.y * a[1] + w.z * a[2] + w.w * a[3];
            }
        }
        __syncthreads();
    }
    for (int n = 0; n < NB; n++) out_ctx[n * 512 + eo] = acc[n] + bc[eo];
}

// ---------------- launch ----------------
extern "C" void kernel_launch(void* const* d_in, const int* in_sizes, int n_in,
                              void* d_out, int out_size, void* d_ws, size_t ws_size,
                              hipStream_t stream)
{
    (void)in_sizes; (void)n_in; (void)out_size; (void)ws_size;
    const float* enc_pad  = (const float*)d_in[0];
    const int*   enc_len  = (const int*)  d_in[1];
    const float* dec_prev = (const float*)d_in[2];
    const float* ali_prev = (const float*)d_in[3];
    const float* We = (const float*)d_in[4];
    const float* be = (const float*)d_in[5];
    const float* Wk = (const float*)d_in[6];
    const float* Wd = (const float*)d_in[7];
    const float* WF = (const float*)d_in[8];
    const float* bF = (const float*)d_in[9];
    const float* Wa = (const float*)d_in[10];
    const float* Ww = (const float*)d_in[11];
    const float* Wc = (const float*)d_in[12];
    const float* bc = (const float*)d_in[13];

    char* ws = (char*)d_ws;
    u16*   Abf  = (u16*)  (ws);                 // 16*2048*512*2 = 33,554,432 B
    u16*   Wkbf = (u16*)  (ws + 33554432);      //  2,097,152 B
    float* fbuf = (float*)(ws + 35651584);      //  5,120,000 B
    float* decp = (float*)(ws + 40771584);      //    131,072 B
    float* spart= (float*)(ws + 40902656);      //  2,048,000 B
    float* aep  = (float*)(ws + 42950656);      //  2,097,152 B
    float* ctmp = (float*)(ws + 45047808);      //    131,072 B  (total ~45.2 MB)

    float* ali = (float*)d_out;                 // [16][4][2000]
    float* ctx = (float*)d_out + NB * HH * TT;  // [16][512]

    convert_kernel <<<8704, 256, 0, stream>>>(enc_pad, Wk, Abf, Wkbf);
    conv_f_kernel  <<<256,  256, 0, stream>>>(ali_prev, WF, bF, fbuf);
    dec_part_kernel<<<8,    256, 0, stream>>>(dec_prev, Wd, decp);
    dim3 g(16, 16, 16);
    score_gemm_kernel<<<g,  256, 0, stream>>>(Abf, Wkbf, fbuf, decp, Wa, Ww, spart);
    softmax_kernel <<<64,   256, 0, stream>>>(spart, enc_len, ali);
    a_enc_kernel   <<<256,  256, 0, stream>>>(ali, enc_pad, aep);
    ctx_tmp_kernel <<<8,    256, 0, stream>>>(aep, We, be, ctmp);
    ctx_out_kernel <<<2,    256, 0, stream>>>(ctmp, Wc, bc, ctx);
}

// Round 3
// 314.684 us; speedup vs baseline: 1.6083x; 1.6083x over previous
//
#include <hip/hip_runtime.h>

// ---------------- problem dims ----------------
#define NB   16
#define TT   2000
#define TP   2048      // padded T for GEMM tiling
#define ENC  512
#define ATTD 512
#define HH   4
#define CC   10
#define KK   64        // conv half-window
#define KW   129       // 2K+1
#define HATT 2048

typedef unsigned short u16;
typedef __attribute__((ext_vector_type(8))) short bf16x8;
typedef __attribute__((ext_vector_type(4))) float f32x4;

#define AS1 __attribute__((address_space(1)))
#define AS3 __attribute__((address_space(3)))

// round-to-nearest-even f32 -> bf16, packed pair
__device__ inline unsigned bfpack2(float lo, float hi) {
    unsigned a = __builtin_bit_cast(unsigned, lo);
    unsigned b = __builtin_bit_cast(unsigned, hi);
    a = (a + 0x7fffu + ((a >> 16) & 1u)) >> 16;
    b = (b + 0x7fffu + ((b >> 16) & 1u)) >> 16;
    return a | (b << 16);
}

__device__ inline float ftanh(float x) {
    float xc = fminf(fmaxf(x, -15.f), 15.f);
    float e = __expf(2.f * xc);
    return (e - 1.f) / (e + 1.f);
}

// ---------------- 1. fused prep: convert + conv_f + dec_part -------------------
// blocks [0,8704): bf16 convert; [8704,8960): conv1d; [8960,8992): dec partials
__global__ __launch_bounds__(256) void prep_kernel(
    const float* __restrict__ enc, const float* __restrict__ Wk,
    const float* __restrict__ ali_prev, const float* __restrict__ WF,
    const float* __restrict__ bF, const float* __restrict__ dec_prev,
    const float* __restrict__ Wd,
    u16* __restrict__ Abf, u16* __restrict__ Wkbf,
    float* __restrict__ fbuf, float* __restrict__ decp)
{
    __shared__ union {
        struct { float aliW[628]; float wf[CC][KW]; float bfs[CC]; } cv;
        float dsl[16 * 128];
    } sm;
    const int bid = blockIdx.x, tid = threadIdx.x;

    if (bid < 8704) {
        // ---- bf16 convert (A zero-padded to TP rows) ----
        long long gid = ((long long)bid * 256 + tid) * 8;
        const long long ATOT = (long long)NB * TP * ENC;   // 1<<24
        if (gid < ATOT) {
            int n = (int)(gid >> 20);
            int rem = (int)(gid & ((1 << 20) - 1));
            int r = rem >> 9, e = rem & 511;
            uint4 out;
            if (r < TT) {
                const float* s = enc + ((long long)n * TT + r) * ENC + e;
                float4 v0 = *(const float4*)s;
                float4 v1 = *(const float4*)(s + 4);
                out.x = bfpack2(v0.x, v0.y); out.y = bfpack2(v0.z, v0.w);
                out.z = bfpack2(v1.x, v1.y); out.w = bfpack2(v1.z, v1.w);
            } else {
                out.x = out.y = out.z = out.w = 0u;
            }
            *(uint4*)(Abf + gid) = out;
        } else {
            long long j = gid - ATOT;                       // < 2048*512
            const float* s = Wk + j;
            float4 v0 = *(const float4*)s;
            float4 v1 = *(const float4*)(s + 4);
            uint4 out;
            out.x = bfpack2(v0.x, v0.y); out.y = bfpack2(v0.z, v0.w);
            out.z = bfpack2(v1.x, v1.y); out.w = bfpack2(v1.z, v1.w);
            *(uint4*)(Wkbf + j) = out;
        }
    } else if (bid < 8960) {
        // ---- grouped conv1d: f[n][h][c][t] ----
        int b2 = bid - 8704;
        int tc = b2 & 3, h = (b2 >> 2) & 3, n = b2 >> 4;
        int t0 = tc * 500;
        const float* arow = ali_prev + ((long long)n * HH + h) * TT;
        for (int i = tid; i < 628; i += 256) {
            int tt = t0 - KK + i;
            sm.cv.aliW[i] = (tt >= 0 && tt < TT) ? arow[tt] : 0.f;
        }
        for (int i = tid; i < CC * KW; i += 256) {
            int c = i / KW, k = i - c * KW;
            sm.cv.wf[c][k] = WF[(h * CC + c) * KW + k];
        }
        if (tid < CC) sm.cv.bfs[tid] = bF[h * CC + tid];
        __syncthreads();
        for (int idx = tid; idx < CC * 500; idx += 256) {
            int c = idx / 500, tl = idx - c * 500;
            float acc = sm.cv.bfs[c];
            for (int k = 0; k < KW; k++) acc += sm.cv.aliW[tl + k] * sm.cv.wf[c][k];
            fbuf[(((long long)n * HH + h) * CC + c) * TT + t0 + tl] = acc;
        }
    } else {
        // ---- dec_part K-split partials: decp[kc][n][d] ----
        int b2 = bid - 8960;                 // 0..31
        int kc = b2 >> 3, jc = b2 & 7;
        for (int i = tid; i < 2048; i += 256) {
            int nn = i >> 7, kk = i & 127;
            sm.dsl[i] = dec_prev[nn * 512 + kc * 128 + kk];
        }
        __syncthreads();
        int d = jc * 256 + tid;
        float acc[NB];
        #pragma unroll
        for (int n = 0; n < NB; n++) acc[n] = 0.f;
        const float4* w4 = (const float4*)(Wd + (long long)d * 512 + kc * 128);
        for (int e4 = 0; e4 < 32; e4++) {
            float4 w = w4[e4];
            #pragma unroll
            for (int n = 0; n < NB; n++) {
                const float* a = sm.dsl + n * 128 + e4 * 4;
                acc[n] += w.x * a[0] + w.y * a[1] + w.z * a[2] + w.w * a[3];
            }
        }
        #pragma unroll
        for (int n = 0; n < NB; n++) decp[((long long)kc * NB + n) * HATT + d] = acc[n];
    }
}

// ---------------- 2. big fused GEMM: kp + tanh-score reduction -----------------
// 1D grid 4096, XCD-swizzled; 2-phase dbuf; T2 XOR LDS swizzle; epilogue overlay
__global__ __launch_bounds__(256) void score_gemm_kernel(
    const u16* __restrict__ Abf, const u16* __restrict__ Bbf,
    const float* __restrict__ fbuf, const float* __restrict__ decp,
    const float* __restrict__ Wa, const float* __restrict__ Ww,
    float* __restrict__ score_part)
{
    __shared__ __attribute__((aligned(16))) char smem[65536];  // 2 x (lA 16K + lB 16K)
    // epilogue overlay (valid after final K-loop barrier)
    float* fT   = (float*)smem;                 // [CC][128]   5120 B
    float* waS  = fT + CC * 128;                // [128][CC]   5120 B
    float* wwS  = waS + 128 * CC;               // [128]
    float* decS = wwS + 128;                    // [128]
    float* sred = decS + 128;                   // [2][128]

    const int bid = blockIdx.x;
    const int swz = (bid & 7) * 512 + (bid >> 3);   // T1: contiguous chunk per XCD
    const int nt = swz & 15, mt = (swz >> 4) & 15, n = swz >> 8;
    const int tid = threadIdx.x, wave = tid >> 6, lane = tid & 63;
    const int l16 = lane & 15, lk = lane >> 4;
    const int h = nt >> 2;

    const u16* Aptr = Abf + ((long long)n * TP + mt * 128) * ENC;
    const u16* Bptr = Bbf + (long long)nt * 128 * ENC;

    f32x4 acc[4][4];
    #pragma unroll
    for (int mi = 0; mi < 4; mi++)
        #pragma unroll
        for (int nj = 0; nj < 4; nj++) {
            f32x4 z = {0.f, 0.f, 0.f, 0.f};
            acc[mi][nj] = z;
        }

    const int wrow = (wave >> 1) * 64, wcol = (wave & 1) * 64;

    // staging: linear LDS dest (wave-uniform base + lane*16), inverse-swizzled
    // global source so reads can use byte ^= (row&7)<<4 (rule #21)
    #define STAGE(buf, k0)                                                        \
        {                                                                         \
            char* base = smem + (buf) * 32768;                                    \
            _Pragma("unroll")                                                     \
            for (int i = 0; i < 4; i++) {                                         \
                int b = i * 4096 + tid * 16;                                      \
                int r = b >> 7, kb = b & 127;                                     \
                int kbs = kb ^ ((r & 7) << 4);                                    \
                __builtin_amdgcn_global_load_lds(                                 \
                    (const AS1 void*)(Aptr + r * ENC + (k0) + (kbs >> 1)),        \
                    (AS3 void*)(base + i * 4096 + wave * 1024), 16, 0, 0);        \
                __builtin_amdgcn_global_load_lds(                                 \
                    (const AS1 void*)(Bptr + r * ENC + (k0) + (kbs >> 1)),        \
                    (AS3 void*)(base + 16384 + i * 4096 + wave * 1024), 16, 0, 0);\
            }                                                                     \
        }

    STAGE(0, 0);
    __syncthreads();                 // compiler drains vmcnt before barrier
    int cur = 0;
    for (int kt = 0; kt < 8; kt++) {
        if (kt < 7) STAGE(cur ^ 1, (kt + 1) * 64);   // prefetch next tile
        const char* lAc = smem + cur * 32768;
        const char* lBc = lAc + 16384;
        #pragma unroll
        for (int ks = 0; ks < 64; ks += 32) {
            bf16x8 af[4], bf[4];
            #pragma unroll
            for (int mi = 0; mi < 4; mi++) {
                int row = wrow + mi * 16 + l16;
                int cb = (ks * 2 + lk * 16) ^ ((row & 7) << 4);
                af[mi] = *(const bf16x8*)(lAc + row * 128 + cb);
            }
            #pragma unroll
            for (int nj = 0; nj < 4; nj++) {
                int row = wcol + nj * 16 + l16;
                int cb = (ks * 2 + lk * 16) ^ ((row & 7) << 4);
                bf[nj] = *(const bf16x8*)(lBc + row * 128 + cb);
            }
            #pragma unroll
            for (int mi = 0; mi < 4; mi++)
                #pragma unroll
                for (int nj = 0; nj < 4; nj++)
                    acc[mi][nj] = __builtin_amdgcn_mfma_f32_16x16x32_bf16(
                        af[mi], bf[nj], acc[mi][nj], 0, 0, 0);
        }
        __syncthreads();             // joins waves; prefetch landed (vmcnt drain)
        cur ^= 1;
    }
    #undef STAGE

    // ---- epilogue: overlay staging (safe: all LDS reads drained at barrier) ----
    const int t0 = mt * 128, dd0 = (nt & 3) * 128;
    for (int i = tid; i < CC * 128; i += 256) {
        int c = i >> 7, r = i & 127;
        int t = t0 + r;
        fT[c * 128 + r] = (t < TT) ? fbuf[(((long long)n * HH + h) * CC + c) * TT + t] : 0.f;
    }
    for (int i = tid; i < 128 * CC; i += 256) {
        int col = i / CC, c = i - col * CC;
        waS[i] = Wa[((long long)h * ATTD + dd0 + col) * CC + c];
    }
    if (tid < 128) {
        int d = nt * 128 + tid;
        wwS[tid] = Ww[h * ATTD + dd0 + tid];
        decS[tid] = decp[((long long)0 * NB + n) * HATT + d]
                  + decp[((long long)1 * NB + n) * HATT + d]
                  + decp[((long long)2 * NB + n) * HATT + d]
                  + decp[((long long)3 * NB + n) * HATT + d];
    }
    __syncthreads();

    // per-lane hoists: this lane's 4 columns (cl = wcol + nj*16 + l16)
    float ww4[4], dec4[4], wa4[4][CC];
    #pragma unroll
    for (int nj = 0; nj < 4; nj++) {
        int cl = wcol + nj * 16 + l16;
        ww4[nj] = wwS[cl];
        dec4[nj] = decS[cl];
        #pragma unroll
        for (int c = 0; c < CC; c++) wa4[nj][c] = waS[cl * CC + c];
    }

    #pragma unroll
    for (int mi = 0; mi < 4; mi++) {
        #pragma unroll
        for (int j = 0; j < 4; j++) {
            int rl = wrow + mi * 16 + lk * 4 + j;
            float f10[CC];
            #pragma unroll
            for (int c = 0; c < CC; c++) f10[c] = fT[c * 128 + rl];  // broadcast
            float s = 0.f;
            #pragma unroll
            for (int nj = 0; nj < 4; nj++) {
                float att = 0.f;
                #pragma unroll
                for (int c = 0; c < CC; c++) att += wa4[nj][c] * f10[c];
                float v = acc[mi][nj][j] + dec4[nj] + att;
                s += ww4[nj] * ftanh(v);
            }
            s += __shfl_xor(s, 1); s += __shfl_xor(s, 2);
            s += __shfl_xor(s, 4); s += __shfl_xor(s, 8);
            if (l16 == 0) sred[(wave & 1) * 128 + rl] = s;
        }
    }
    __syncthreads();
    if (tid < 128) {
        int t = t0 + tid;
        if (t < TT)
            score_part[((long long)((nt & 3) * NB + n) * HH + h) * TT + t] =
                sred[tid] + sred[128 + tid];
    }
}

// ---------------- 3. masked softmax over t (sums the 4 partial slices) ---------
__global__ __launch_bounds__(256) void softmax_kernel(
    const float* __restrict__ score_part, const int* __restrict__ enc_len,
    float* __restrict__ ali)
{
    int n = blockIdx.x >> 2, h = blockIdx.x & 3;
    int len = enc_len[n];
    int tid = threadIdx.x;
    float s[8];
    float lmax = -3.4e38f;
    #pragma unroll
    for (int i = 0; i < 8; i++) {
        int t = tid + i * 256;
        float v = -3.4e38f;
        if (t < len) {
            v = 0.f;
            #pragma unroll
            for (int q = 0; q < 4; q++)
                v += score_part[((long long)(q * NB + n) * HH + h) * TT + t];
        }
        s[i] = v;
        lmax = fmaxf(lmax, v);
    }
    __shared__ float red[256];
    red[tid] = lmax; __syncthreads();
    for (int off = 128; off; off >>= 1) {
        if (tid < off) red[tid] = fmaxf(red[tid], red[tid + off]);
        __syncthreads();
    }
    float bmax = red[0];
    __syncthreads();
    float lsum = 0.f;
    #pragma unroll
    for (int i = 0; i < 8; i++) {
        int t = tid + i * 256;
        if (t < len) { s[i] = expf(s[i] - bmax); lsum += s[i]; }
        else s[i] = 0.f;
    }
    red[tid] = lsum; __syncthreads();
    for (int off = 128; off; off >>= 1) {
        if (tid < off) red[tid] += red[tid + off];
        __syncthreads();
    }
    float inv = 1.f / red[0];
    float* arow = ali + ((long long)n * HH + h) * TT;
    #pragma unroll
    for (int i = 0; i < 8; i++) {
        int t = tid + i * 256;
        if (t < TT) arow[t] = s[i] * inv;
    }
}

// ---------------- 4. a_enc partials (skip chunks past enc_len) -----------------
__global__ __launch_bounds__(256) void a_enc_kernel(
    const float* __restrict__ ali, const float* __restrict__ enc_pad,
    const int* __restrict__ enc_len, float* __restrict__ a_enc_part)
{
    int tc = blockIdx.x & 15, n = blockIdx.x >> 4;
    int tid = threadIdx.x;
    int len = enc_len[n];
    int tbeg = tc * 125;
    int cnt = len - tbeg; if (cnt > 125) cnt = 125; if (cnt < 0) cnt = 0;
    float acc[HH][2];
    #pragma unroll
    for (int hh = 0; hh < HH; hh++) { acc[hh][0] = 0.f; acc[hh][1] = 0.f; }
    for (int tt = 0; tt < cnt; tt++) {
        int t = tbeg + tt;
        float w0 = ali[((long long)n * HH + 0) * TT + t];
        float w1 = ali[((long long)n * HH + 1) * TT + t];
        float w2 = ali[((long long)n * HH + 2) * TT + t];
        float w3 = ali[((long long)n * HH + 3) * TT + t];
        float2 ev = *(const float2*)(enc_pad + ((long long)n * TT + t) * ENC + tid * 2);
        acc[0][0] += w0 * ev.x; acc[0][1] += w0 * ev.y;
        acc[1][0] += w1 * ev.x; acc[1][1] += w1 * ev.y;
        acc[2][0] += w2 * ev.x; acc[2][1] += w2 * ev.y;
        acc[3][0] += w3 * ev.x; acc[3][1] += w3 * ev.y;
    }
    #pragma unroll
    for (int hh = 0; hh < HH; hh++) {
        a_enc_part[(((long long)tc * NB + n) * HH + hh) * ENC + tid * 2 + 0] = acc[hh][0];
        a_enc_part[(((long long)tc * NB + n) * HH + hh) * ENC + tid * 2 + 1] = acc[hh][1];
    }
}

// ---------------- 5. ctx_tmp partials (K-split, grid 32) -----------------------
__global__ __launch_bounds__(256) void ctx_tmp_kernel(
    const float* __restrict__ a_enc_part, const float* __restrict__ We,
    const float* __restrict__ be, float* __restrict__ ctmp)
{
    int kc = blockIdx.x >> 3, jc = blockIdx.x & 7;
    int tid = threadIdx.x;
    int j = jc * 256 + tid;
    int h = j >> 9;                       // uniform per block
    __shared__ float aes[16 * 128];
    for (int i = tid; i < 2048; i += 256) {
        int nn = i >> 7, kk = i & 127;
        float s = 0.f;
        for (int tc = 0; tc < 16; tc++)
            s += a_enc_part[(((long long)tc * NB + nn) * HH + h) * ENC + kc * 128 + kk];
        aes[i] = s;
    }
    __syncthreads();
    float acc[NB];
    #pragma unroll
    for (int n = 0; n < NB; n++) acc[n] = 0.f;
    const float4* w4 = (const float4*)(We + (long long)j * 512 + kc * 128);
    for (int e4 = 0; e4 < 32; e4++) {
        float4 w = w4[e4];
        #pragma unroll
        for (int n = 0; n < NB; n++) {
            const float* a = aes + n * 128 + e4 * 4;
            acc[n] += w.x * a[0] + w.y * a[1] + w.z * a[2] + w.w * a[3];
        }
    }
    float bias = (kc == 0) ? be[j] : 0.f;
    #pragma unroll
    for (int n = 0; n < NB; n++)
        ctmp[((long long)kc * NB + n) * HATT + j] = acc[n] + bias;
}

// ---------------- 6. ctx_out (grid 16 = 8 eo-chunks x 2 n-chunks) --------------
__global__ __launch_bounds__(256) void ctx_out_kernel(
    const float* __restrict__ ctmp, const float* __restrict__ Wc,
    const float* __restrict__ bc, float* __restrict__ out_ctx)
{
    int ec = blockIdx.x & 7, nc = blockIdx.x >> 3;
    int tid = threadIdx.x;
    __shared__ float ct[8 * 2048];        // 64 KB: ct[nn][j], nn = local n
    __shared__ float red[4][64][8];       // 8 KB
    for (int i = tid; i < 8 * 2048; i += 256) {
        int nn = i >> 11, j = i & 2047;
        int n = nc * 8 + nn;
        ct[i] = ctmp[((long long)0 * NB + n) * HATT + j]
              + ctmp[((long long)1 * NB + n) * HATT + j]
              + ctmp[((long long)2 * NB + n) * HATT + j]
              + ctmp[((long long)3 * NB + n) * HATT + j];
    }
    __syncthreads();
    int eo = tid & 63, kq = tid >> 6;     // 64 eo x 4 K-quarters
    int eg = ec * 64 + eo;
    float acc[8];
    #pragma unroll
    for (int nn = 0; nn < 8; nn++) acc[nn] = 0.f;
    const float4* w4 = (const float4*)(Wc + (long long)eg * HATT + kq * 512);
    for (int j4 = 0; j4 < 128; j4++) {
        float4 w = w4[j4];
        #pragma unroll
        for (int nn = 0; nn < 8; nn++) {
            const float* a = ct + nn * 2048 + kq * 512 + j4 * 4;
            acc[nn] += w.x * a[0] + w.y * a[1] + w.z * a[2] + w.w * a[3];
        }
    }
    #pragma unroll
    for (int nn = 0; nn < 8; nn++) red[kq][eo][nn] = acc[nn];
    __syncthreads();
    #pragma unroll
    for (int r = 0; r < 2; r++) {
        int idx = tid + r * 256;
        int eo2 = idx & 63, nn2 = idx >> 6;   // nn2 0..7
        float s = red[0][eo2][nn2] + red[1][eo2][nn2]
                + red[2][eo2][nn2] + red[3][eo2][nn2];
        out_ctx[((long long)(nc * 8 + nn2)) * 512 + ec * 64 + eo2] = s + bc[ec * 64 + eo2];
    }
}

// ---------------- launch ----------------
extern "C" void kernel_launch(void* const* d_in, const int* in_sizes, int n_in,
                              void* d_out, int out_size, void* d_ws, size_t ws_size,
                              hipStream_t stream)
{
    (void)in_sizes; (void)n_in; (void)out_size; (void)ws_size;
    const float* enc_pad  = (const float*)d_in[0];
    const int*   enc_len  = (const int*)  d_in[1];
    const float* dec_prev = (const float*)d_in[2];
    const float* ali_prev = (const float*)d_in[3];
    const float* We = (const float*)d_in[4];
    const float* be = (const float*)d_in[5];
    const float* Wk = (const float*)d_in[6];
    const float* Wd = (const float*)d_in[7];
    const float* WF = (const float*)d_in[8];
    const float* bF = (const float*)d_in[9];
    const float* Wa = (const float*)d_in[10];
    const float* Ww = (const float*)d_in[11];
    const float* Wc = (const float*)d_in[12];
    const float* bc = (const float*)d_in[13];

    char* ws = (char*)d_ws;
    u16*   Abf  = (u16*)  (ws);                 // 33,554,432 B
    u16*   Wkbf = (u16*)  (ws + 33554432);      //  2,097,152 B
    float* fbuf = (float*)(ws + 35651584);      //  5,120,000 B
    float* decp = (float*)(ws + 40771584);      //    524,288 B  [4][16][2048]
    float* spart= (float*)(ws + 41295872);      //  2,048,000 B
    float* aep  = (float*)(ws + 43343872);      //  2,097,152 B
    float* ctmp = (float*)(ws + 40771584);      // alias decp (dead after score_gemm)

    float* ali = (float*)d_out;                 // [16][4][2000]
    float* ctx = (float*)d_out + NB * HH * TT;  // [16][512]

    prep_kernel      <<<8992, 256, 0, stream>>>(enc_pad, Wk, ali_prev, WF, bF,
                                                dec_prev, Wd, Abf, Wkbf, fbuf, decp);
    score_gemm_kernel<<<4096, 256, 0, stream>>>(Abf, Wkbf, fbuf, decp, Wa, Ww, spart);
    softmax_kernel   <<<64,   256, 0, stream>>>(spart, enc_len, ali);
    a_enc_kernel     <<<256,  256, 0, stream>>>(ali, enc_pad, enc_len, aep);
    ctx_tmp_kernel   <<<32,   256, 0, stream>>>(aep, We, be, ctmp);
    ctx_out_kernel   <<<16,   256, 0, stream>>>(ctmp, Wc, bc, ctx);
}

// Round 4
// 231.613 us; speedup vs baseline: 2.1851x; 1.3587x over previous
//
#include <hip/hip_runtime.h>

// ---------------- problem dims ----------------
#define NB   16
#define TT   2000
#define TP   2048      // padded T for GEMM tiling
#define ENC  512
#define ATTD 512
#define HH   4
#define CC   10
#define KK   64        // conv half-window
#define KW   129       // 2K+1
#define HATT 2048

typedef unsigned short u16;
typedef __attribute__((ext_vector_type(8))) short bf16x8;
typedef __attribute__((ext_vector_type(4))) float f32x4;

#define AS1 __attribute__((address_space(1)))
#define AS3 __attribute__((address_space(3)))

// round-to-nearest-even f32 -> bf16, packed pair
__device__ inline unsigned bfpack2(float lo, float hi) {
    unsigned a = __builtin_bit_cast(unsigned, lo);
    unsigned b = __builtin_bit_cast(unsigned, hi);
    a = (a + 0x7fffu + ((a >> 16) & 1u)) >> 16;
    b = (b + 0x7fffu + ((b >> 16) & 1u)) >> 16;
    return a | (b << 16);
}

// ---------------- 1. fused prep: convert + conv_f + dec_part -------------------
// blocks [0,8704): bf16 convert; [8704,8960): conv1d; [8960,8992): dec partials
__global__ __launch_bounds__(256) void prep_kernel(
    const float* __restrict__ enc, const float* __restrict__ Wk,
    const float* __restrict__ ali_prev, const float* __restrict__ WF,
    const float* __restrict__ bF, const float* __restrict__ dec_prev,
    const float* __restrict__ Wd,
    u16* __restrict__ Abf, u16* __restrict__ Wkbf,
    float* __restrict__ fbuf, float* __restrict__ decp)
{
    __shared__ union {
        struct { float aliW[632]; float wfT[KW * CC]; float bfs[CC]; } cv;
        float dsl[16 * 128];
    } sm;
    const int bid = blockIdx.x, tid = threadIdx.x;

    if (bid < 8704) {
        // ---- bf16 convert (A zero-padded to TP rows) ----
        long long gid = ((long long)bid * 256 + tid) * 8;
        const long long ATOT = (long long)NB * TP * ENC;   // 1<<24
        if (gid < ATOT) {
            int n = (int)(gid >> 20);
            int rem = (int)(gid & ((1 << 20) - 1));
            int r = rem >> 9, e = rem & 511;
            uint4 out;
            if (r < TT) {
                const float* s = enc + ((long long)n * TT + r) * ENC + e;
                float4 v0 = *(const float4*)s;
                float4 v1 = *(const float4*)(s + 4);
                out.x = bfpack2(v0.x, v0.y); out.y = bfpack2(v0.z, v0.w);
                out.z = bfpack2(v1.x, v1.y); out.w = bfpack2(v1.z, v1.w);
            } else {
                out.x = out.y = out.z = out.w = 0u;
            }
            *(uint4*)(Abf + gid) = out;
        } else {
            long long j = gid - ATOT;                       // < 2048*512
            const float* s = Wk + j;
            float4 v0 = *(const float4*)s;
            float4 v1 = *(const float4*)(s + 4);
            uint4 out;
            out.x = bfpack2(v0.x, v0.y); out.y = bfpack2(v0.z, v0.w);
            out.z = bfpack2(v1.x, v1.y); out.w = bfpack2(v1.z, v1.w);
            *(uint4*)(Wkbf + j) = out;
        }
    } else if (bid < 8960) {
        // ---- grouped conv1d, register-accumulator form ----
        // 256 blocks = n(16) x h(4) x tc(4); thread owns t = t0+2*tid, +1
        int b2 = bid - 8704;
        int tc = b2 & 3, h = (b2 >> 2) & 3, n = b2 >> 4;
        int t0 = tc * 500;
        float* aliW = sm.cv.aliW;
        float* wfT  = sm.cv.wfT;       // [k][c] layout
        float* bfs  = sm.cv.bfs;
        const float* arow = ali_prev + ((long long)n * HH + h) * TT;
        for (int i = tid; i < 632; i += 256) {
            int tt = t0 - KK + i;
            aliW[i] = (tt >= 0 && tt < TT) ? arow[tt] : 0.f;
        }
        for (int i = tid; i < KW * CC; i += 256) {
            int k = i / CC, c = i - k * CC;
            wfT[i] = WF[(h * CC + c) * KW + k];
        }
        if (tid < CC) bfs[tid] = bF[h * CC + tid];
        __syncthreads();
        if (tid < 250) {
            float acc0[CC], acc1[CC];
            #pragma unroll
            for (int c = 0; c < CC; c++) { acc0[c] = 0.f; acc1[c] = 0.f; }
            const int base = 2 * tid;
            float2 w0 = *(const float2*)&aliW[base];
            for (int k = 0; k < 128; k += 2) {
                float2 w2 = *(const float2*)&aliW[base + k + 2];
                #pragma unroll
                for (int cj = 0; cj < 5; cj++) {
                    float2 fk  = *(const float2*)&wfT[k * CC + cj * 2];
                    float2 fk1 = *(const float2*)&wfT[(k + 1) * CC + cj * 2];
                    acc0[2*cj]   += w0.x * fk.x + w0.y * fk1.x;
                    acc0[2*cj+1] += w0.x * fk.y + w0.y * fk1.y;
                    acc1[2*cj]   += w0.y * fk.x + w2.x * fk1.x;
                    acc1[2*cj+1] += w0.y * fk.y + w2.x * fk1.y;
                }
                w0 = w2;
            }
            // tail tap k=128 (w0 = aliW[base+128..129])
            #pragma unroll
            for (int cj = 0; cj < 5; cj++) {
                float2 fk = *(const float2*)&wfT[128 * CC + cj * 2];
                acc0[2*cj]   += w0.x * fk.x;  acc0[2*cj+1] += w0.x * fk.y;
                acc1[2*cj]   += w0.y * fk.x;  acc1[2*cj+1] += w0.y * fk.y;
            }
            int t = t0 + base;
            #pragma unroll
            for (int c = 0; c < CC; c++) {
                float* fp = fbuf + (((long long)n * HH + h) * CC + c) * TT + t;
                fp[0] = acc0[c] + bfs[c];
                fp[1] = acc1[c] + bfs[c];
            }
        }
    } else {
        // ---- dec_part K-split partials: decp[kc][n][d] ----
        int b2 = bid - 8960;                 // 0..31
        int kc = b2 >> 3, jc = b2 & 7;
        for (int i = tid; i < 2048; i += 256) {
            int nn = i >> 7, kk = i & 127;
            sm.dsl[i] = dec_prev[nn * 512 + kc * 128 + kk];
        }
        __syncthreads();
        int d = jc * 256 + tid;
        float acc[NB];
        #pragma unroll
        for (int n = 0; n < NB; n++) acc[n] = 0.f;
        const float4* w4 = (const float4*)(Wd + (long long)d * 512 + kc * 128);
        for (int e4 = 0; e4 < 32; e4++) {
            float4 w = w4[e4];
            #pragma unroll
            for (int n = 0; n < NB; n++) {
                const float* a = sm.dsl + n * 128 + e4 * 4;
                acc[n] += w.x * a[0] + w.y * a[1] + w.z * a[2] + w.w * a[3];
            }
        }
        #pragma unroll
        for (int n = 0; n < NB; n++) decp[((long long)kc * NB + n) * HATT + d] = acc[n];
    }
}

// ---------------- 2. big fused GEMM: kp + score reduction ----------------------
// m97 structure: single 32KB buffer, BK=64, 2 barriers/K-step, 4 blocks/CU
__global__ __launch_bounds__(256, 4) void score_gemm_kernel(
    const u16* __restrict__ Abf, const u16* __restrict__ Bbf,
    const float* __restrict__ fbuf, const float* __restrict__ decp,
    const float* __restrict__ Wa, const float* __restrict__ Ww,
    float* __restrict__ score_part)
{
    __shared__ __attribute__((aligned(16))) char smem[32768];  // lA 16K + lB 16K
    // epilogue overlay (valid after final K-loop barrier): 12.3 KB
    float* fT   = (float*)smem;                 // [128][CC] row-major
    float* waS  = fT + 128 * CC;                // [128][CC]
    float* wwS  = waS + 128 * CC;               // [128]
    float* decS = wwS + 128;                    // [128]
    float* sred = decS + 128;                   // [2][128]

    const int bid = blockIdx.x;
    const int swz = (bid & 7) * 512 + (bid >> 3);   // T1: contiguous chunk per XCD
    const int nt = swz & 15, mt = (swz >> 4) & 15, n = swz >> 8;
    const int tid = threadIdx.x, wave = tid >> 6, lane = tid & 63;
    const int l16 = lane & 15, lk = lane >> 4;
    const int h = nt >> 2;

    const u16* Aptr = Abf + ((long long)n * TP + mt * 128) * ENC;
    const u16* Bptr = Bbf + (long long)nt * 128 * ENC;

    f32x4 acc[4][4];
    #pragma unroll
    for (int mi = 0; mi < 4; mi++)
        #pragma unroll
        for (int nj = 0; nj < 4; nj++) {
            f32x4 z = {0.f, 0.f, 0.f, 0.f};
            acc[mi][nj] = z;
        }

    const int wrow = (wave >> 1) * 64, wcol = (wave & 1) * 64;

    // staging: linear LDS dest (wave-uniform base + lane*16), inverse-swizzled
    // global source so reads can use byte ^= (row&7)<<4 (rule #21)
    for (int kt = 0; kt < 8; kt++) {
        const int k0 = kt * 64;
        #pragma unroll
        for (int i = 0; i < 4; i++) {
            int b = i * 4096 + tid * 16;
            int r = b >> 7, kb = b & 127;
            int kbs = kb ^ ((r & 7) << 4);
            __builtin_amdgcn_global_load_lds(
                (const AS1 void*)(Aptr + r * ENC + k0 + (kbs >> 1)),
                (AS3 void*)(smem + i * 4096 + wave * 1024), 16, 0, 0);
            __builtin_amdgcn_global_load_lds(
                (const AS1 void*)(Bptr + r * ENC + k0 + (kbs >> 1)),
                (AS3 void*)(smem + 16384 + i * 4096 + wave * 1024), 16, 0, 0);
        }
        __syncthreads();    // drains vmcnt(0): tiles resident
        #pragma unroll
        for (int ks = 0; ks < 64; ks += 32) {
            bf16x8 af[4], bf[4];
            #pragma unroll
            for (int mi = 0; mi < 4; mi++) {
                int row = wrow + mi * 16 + l16;
                int cb = (ks * 2 + lk * 16) ^ ((row & 7) << 4);
                af[mi] = *(const bf16x8*)(smem + row * 128 + cb);
            }
            #pragma unroll
            for (int nj = 0; nj < 4; nj++) {
                int row = wcol + nj * 16 + l16;
                int cb = (ks * 2 + lk * 16) ^ ((row & 7) << 4);
                bf[nj] = *(const bf16x8*)(smem + 16384 + row * 128 + cb);
            }
            #pragma unroll
            for (int mi = 0; mi < 4; mi++)
                #pragma unroll
                for (int nj = 0; nj < 4; nj++)
                    acc[mi][nj] = __builtin_amdgcn_mfma_f32_16x16x32_bf16(
                        af[mi], bf[nj], acc[mi][nj], 0, 0, 0);
        }
        __syncthreads();    // all reads done before next stage overwrites
    }

    // ---- epilogue (overlays smem; softmax-invariant form):
    // score'[t] = sum_d -2*ww_d * rcp(exp(2*v)+1)   [shift by -sum(ww) cancels]
    const int t0 = mt * 128, dd0 = (nt & 3) * 128;
    for (int i = tid; i < 128 * CC; i += 256) {
        int r = i / CC, c = i - r * CC;
        int t = t0 + r;
        fT[i] = (t < TT) ? fbuf[(((long long)n * HH + h) * CC + c) * TT + t] : 0.f;
    }
    for (int i = tid; i < 128 * CC; i += 256) {
        int col = i / CC, c = i - col * CC;
        waS[i] = Wa[((long long)h * ATTD + dd0 + col) * CC + c];
    }
    if (tid < 128) {
        int d = nt * 128 + tid;
        wwS[tid] = Ww[h * ATTD + dd0 + tid];
        decS[tid] = decp[((long long)0 * NB + n) * HATT + d]
                  + decp[((long long)1 * NB + n) * HATT + d]
                  + decp[((long long)2 * NB + n) * HATT + d]
                  + decp[((long long)3 * NB + n) * HATT + d];
    }
    __syncthreads();

    // per-lane hoists: this lane's 4 columns (cl = wcol + nj*16 + l16)
    float wm2[4], dec4[4], wa4[4][CC];
    #pragma unroll
    for (int nj = 0; nj < 4; nj++) {
        int cl = wcol + nj * 16 + l16;
        wm2[nj] = -2.f * wwS[cl];
        dec4[nj] = decS[cl];
        #pragma unroll
        for (int c = 0; c < CC; c++) wa4[nj][c] = waS[cl * CC + c];
    }

    #pragma unroll
    for (int mi = 0; mi < 4; mi++) {
        #pragma unroll
        for (int j = 0; j < 4; j++) {
            int rl = wrow + mi * 16 + lk * 4 + j;
            float f10[CC];
            #pragma unroll
            for (int cj = 0; cj < 5; cj++) {              // broadcast float2 reads
                float2 fp = *(const float2*)&fT[rl * CC + cj * 2];
                f10[2*cj] = fp.x; f10[2*cj+1] = fp.y;
            }
            float s = 0.f;
            #pragma unroll
            for (int nj = 0; nj < 4; nj++) {
                float att = 0.f;
                #pragma unroll
                for (int c = 0; c < CC; c++) att += wa4[nj][c] * f10[c];
                float v = acc[mi][nj][j] + dec4[nj] + att;
                float e = __expf(v + v);
                s = fmaf(wm2[nj], __builtin_amdgcn_rcpf(e + 1.f), s);
            }
            s += __shfl_xor(s, 1); s += __shfl_xor(s, 2);
            s += __shfl_xor(s, 4); s += __shfl_xor(s, 8);
            if (l16 == 0) sred[(wave & 1) * 128 + rl] = s;
        }
    }
    __syncthreads();
    if (tid < 128) {
        int t = t0 + tid;
        if (t < TT)
            score_part[((long long)((nt & 3) * NB + n) * HH + h) * TT + t] =
                sred[tid] + sred[128 + tid];
    }
}

// ---------------- 3. masked softmax over t (sums the 4 partial slices) ---------
__global__ __launch_bounds__(256) void softmax_kernel(
    const float* __restrict__ score_part, const int* __restrict__ enc_len,
    float* __restrict__ ali)
{
    int n = blockIdx.x >> 2, h = blockIdx.x & 3;
    int len = enc_len[n];
    int tid = threadIdx.x;
    float s[8];
    float lmax = -3.4e38f;
    #pragma unroll
    for (int i = 0; i < 8; i++) {
        int t = tid + i * 256;
        float v = -3.4e38f;
        if (t < len) {
            v = 0.f;
            #pragma unroll
            for (int q = 0; q < 4; q++)
                v += score_part[((long long)(q * NB + n) * HH + h) * TT + t];
        }
        s[i] = v;
        lmax = fmaxf(lmax, v);
    }
    __shared__ float red[256];
    red[tid] = lmax; __syncthreads();
    for (int off = 128; off; off >>= 1) {
        if (tid < off) red[tid] = fmaxf(red[tid], red[tid + off]);
        __syncthreads();
    }
    float bmax = red[0];
    __syncthreads();
    float lsum = 0.f;
    #pragma unroll
    for (int i = 0; i < 8; i++) {
        int t = tid + i * 256;
        if (t < len) { s[i] = expf(s[i] - bmax); lsum += s[i]; }
        else s[i] = 0.f;
    }
    red[tid] = lsum; __syncthreads();
    for (int off = 128; off; off >>= 1) {
        if (tid < off) red[tid] += red[tid + off];
        __syncthreads();
    }
    float inv = 1.f / red[0];
    float* arow = ali + ((long long)n * HH + h) * TT;
    #pragma unroll
    for (int i = 0; i < 8; i++) {
        int t = tid + i * 256;
        if (t < TT) arow[t] = s[i] * inv;
    }
}

// ---------------- 4. a_enc partials (grid 1024 = n x 64 t-chunks) --------------
__global__ __launch_bounds__(256) void a_enc_kernel(
    const float* __restrict__ ali, const float* __restrict__ enc_pad,
    const int* __restrict__ enc_len, float* __restrict__ a_enc_part)
{
    int tc = blockIdx.x & 63, n = blockIdx.x >> 6;
    int tid = threadIdx.x;
    int len = enc_len[n];
    int tbeg = tc * 32;
    int cnt = len - tbeg; if (cnt > 32) cnt = 32; if (cnt < 0) cnt = 0;
    float acc[HH][2];
    #pragma unroll
    for (int hh = 0; hh < HH; hh++) { acc[hh][0] = 0.f; acc[hh][1] = 0.f; }
    for (int tt = 0; tt < cnt; tt++) {
        int t = tbeg + tt;
        float w0 = ali[((long long)n * HH + 0) * TT + t];
        float w1 = ali[((long long)n * HH + 1) * TT + t];
        float w2 = ali[((long long)n * HH + 2) * TT + t];
        float w3 = ali[((long long)n * HH + 3) * TT + t];
        float2 ev = *(const float2*)(enc_pad + ((long long)n * TT + t) * ENC + tid * 2);
        acc[0][0] += w0 * ev.x; acc[0][1] += w0 * ev.y;
        acc[1][0] += w1 * ev.x; acc[1][1] += w1 * ev.y;
        acc[2][0] += w2 * ev.x; acc[2][1] += w2 * ev.y;
        acc[3][0] += w3 * ev.x; acc[3][1] += w3 * ev.y;
    }
    #pragma unroll
    for (int hh = 0; hh < HH; hh++) {
        a_enc_part[(((long long)tc * NB + n) * HH + hh) * ENC + tid * 2 + 0] = acc[hh][0];
        a_enc_part[(((long long)tc * NB + n) * HH + hh) * ENC + tid * 2 + 1] = acc[hh][1];
    }
}

// ---------------- 5. ctx_tmp partials (K-split, grid 32) -----------------------
__global__ __launch_bounds__(256) void ctx_tmp_kernel(
    const float* __restrict__ a_enc_part, const float* __restrict__ We,
    const float* __restrict__ be, float* __restrict__ ctmp)
{
    int kc = blockIdx.x >> 3, jc = blockIdx.x & 7;
    int tid = threadIdx.x;
    int j = jc * 256 + tid;
    int h = j >> 9;                       // uniform per block
    __shared__ float aes[16 * 128];
    for (int i = tid; i < 2048; i += 256) {
        int nn = i >> 7, kk = i & 127;
        float s = 0.f;
        for (int tc = 0; tc < 64; tc++)
            s += a_enc_part[(((long long)tc * NB + nn) * HH + h) * ENC + kc * 128 + kk];
        aes[i] = s;
    }
    __syncthreads();
    float acc[NB];
    #pragma unroll
    for (int n = 0; n < NB; n++) acc[n] = 0.f;
    const float4* w4 = (const float4*)(We + (long long)j * 512 + kc * 128);
    for (int e4 = 0; e4 < 32; e4++) {
        float4 w = w4[e4];
        #pragma unroll
        for (int n = 0; n < NB; n++) {
            const float* a = aes + n * 128 + e4 * 4;
            acc[n] += w.x * a[0] + w.y * a[1] + w.z * a[2] + w.w * a[3];
        }
    }
    float bias = (kc == 0) ? be[j] : 0.f;
    #pragma unroll
    for (int n = 0; n < NB; n++)
        ctmp[((long long)kc * NB + n) * HATT + j] = acc[n] + bias;
}

// ---------------- 6. ctx_out (grid 16 = 8 eo-chunks x 2 n-chunks) --------------
__global__ __launch_bounds__(256) void ctx_out_kernel(
    const float* __restrict__ ctmp, const float* __restrict__ Wc,
    const float* __restrict__ bc, float* __restrict__ out_ctx)
{
    int ec = blockIdx.x & 7, nc = blockIdx.x >> 3;
    int tid = threadIdx.x;
    __shared__ float ct[8 * 2048];        // 64 KB: ct[nn][j], nn = local n
    __shared__ float red[4][64][8];       // 8 KB
    for (int i = tid; i < 8 * 2048; i += 256) {
        int nn = i >> 11, j = i & 2047;
        int n = nc * 8 + nn;
        ct[i] = ctmp[((long long)0 * NB + n) * HATT + j]
              + ctmp[((long long)1 * NB + n) * HATT + j]
              + ctmp[((long long)2 * NB + n) * HATT + j]
              + ctmp[((long long)3 * NB + n) * HATT + j];
    }
    __syncthreads();
    int eo = tid & 63, kq = tid >> 6;     // 64 eo x 4 K-quarters
    int eg = ec * 64 + eo;
    float acc[8];
    #pragma unroll
    for (int nn = 0; nn < 8; nn++) acc[nn] = 0.f;
    const float4* w4 = (const float4*)(Wc + (long long)eg * HATT + kq * 512);
    for (int j4 = 0; j4 < 128; j4++) {
        float4 w = w4[j4];
        #pragma unroll
        for (int nn = 0; nn < 8; nn++) {
            const float* a = ct + nn * 2048 + kq * 512 + j4 * 4;
            acc[nn] += w.x * a[0] + w.y * a[1] + w.z * a[2] + w.w * a[3];
        }
    }
    #pragma unroll
    for (int nn = 0; nn < 8; nn++) red[kq][eo][nn] = acc[nn];
    __syncthreads();
    #pragma unroll
    for (int r = 0; r < 2; r++) {
        int idx = tid + r * 256;
        int eo2 = idx & 63, nn2 = idx >> 6;   // nn2 0..7
        float s = red[0][eo2][nn2] + red[1][eo2][nn2]
                + red[2][eo2][nn2] + red[3][eo2][nn2];
        out_ctx[((long long)(nc * 8 + nn2)) * 512 + ec * 64 + eo2] = s + bc[ec * 64 + eo2];
    }
}

// ---------------- launch ----------------
extern "C" void kernel_launch(void* const* d_in, const int* in_sizes, int n_in,
                              void* d_out, int out_size, void* d_ws, size_t ws_size,
                              hipStream_t stream)
{
    (void)in_sizes; (void)n_in; (void)out_size; (void)ws_size;
    const float* enc_pad  = (const float*)d_in[0];
    const int*   enc_len  = (const int*)  d_in[1];
    const float* dec_prev = (const float*)d_in[2];
    const float* ali_prev = (const float*)d_in[3];
    const float* We = (const float*)d_in[4];
    const float* be = (const float*)d_in[5];
    const float* Wk = (const float*)d_in[6];
    const float* Wd = (const float*)d_in[7];
    const float* WF = (const float*)d_in[8];
    const float* bF = (const float*)d_in[9];
    const float* Wa = (const float*)d_in[10];
    const float* Ww = (const float*)d_in[11];
    const float* Wc = (const float*)d_in[12];
    const float* bc = (const float*)d_in[13];

    char* ws = (char*)d_ws;
    u16*   Abf  = (u16*)  (ws);                 // 33,554,432 B (dead after gemm)
    u16*   Wkbf = (u16*)  (ws + 33554432);      //  2,097,152 B
    float* fbuf = (float*)(ws + 35651584);      //  5,120,000 B
    float* decp = (float*)(ws + 40771584);      //    524,288 B  [4][16][2048]
    float* spart= (float*)(ws + 41295872);      //  2,048,000 B
    float* aep  = (float*)(ws);                 // alias Abf: [64][16][4][512] 8 MB
    float* ctmp = (float*)(ws + 40771584);      // alias decp (dead after gemm)

    float* ali = (float*)d_out;                 // [16][4][2000]
    float* ctx = (float*)d_out + NB * HH * TT;  // [16][512]

    prep_kernel      <<<8992, 256, 0, stream>>>(enc_pad, Wk, ali_prev, WF, bF,
                                                dec_prev, Wd, Abf, Wkbf, fbuf, decp);
    score_gemm_kernel<<<4096, 256, 0, stream>>>(Abf, Wkbf, fbuf, decp, Wa, Ww, spart);
    softmax_kernel   <<<64,   256, 0, stream>>>(spart, enc_len, ali);
    a_enc_kernel     <<<1024, 256, 0, stream>>>(ali, enc_pad, enc_len, aep);
    ctx_tmp_kernel   <<<32,   256, 0, stream>>>(aep, We, be, ctmp);
    ctx_out_kernel   <<<16,   256, 0, stream>>>(ctmp, Wc, bc, ctx);
}

// Round 5
// 209.211 us; speedup vs baseline: 2.4191x; 1.1071x over previous
//
#include <hip/hip_runtime.h>

// ---------------- problem dims ----------------
#define NB   16
#define TT   2000
#define TP   2048      // padded T for GEMM tiling
#define ENC  512
#define ATTD 512
#define HH   4
#define CC   10
#define KK   64        // conv half-window
#define KW   129       // 2K+1
#define HATT 2048

typedef unsigned short u16;
typedef __attribute__((ext_vector_type(8))) short bf16x8;
typedef __attribute__((ext_vector_type(4))) float f32x4;

#define AS1 __attribute__((address_space(1)))
#define AS3 __attribute__((address_space(3)))

// round-to-nearest-even f32 -> bf16, packed pair
__device__ inline unsigned bfpack2(float lo, float hi) {
    unsigned a = __builtin_bit_cast(unsigned, lo);
    unsigned b = __builtin_bit_cast(unsigned, hi);
    a = (a + 0x7fffu + ((a >> 16) & 1u)) >> 16;
    b = (b + 0x7fffu + ((b >> 16) & 1u)) >> 16;
    return a | (b << 16);
}

// ---------------- 1. fused prep: convert + conv_f(->bf16 f^T) + dec + Wa pack --
// blocks [0,8704): bf16 convert; [8704,8960): conv1d; [8960,8992): dec partials;
// [8992,8996): Wa -> wab pack
__global__ __launch_bounds__(256) void prep_kernel(
    const float* __restrict__ enc, const float* __restrict__ Wk,
    const float* __restrict__ ali_prev, const float* __restrict__ WF,
    const float* __restrict__ bF, const float* __restrict__ dec_prev,
    const float* __restrict__ Wd, const float* __restrict__ Wa,
    u16* __restrict__ Abf, u16* __restrict__ Wkbf,
    u16* __restrict__ ftb, u16* __restrict__ wab,
    float* __restrict__ decp)
{
    __shared__ union {
        struct { float aliW[632]; float wfT[KW * CC]; float bfs[CC]; } cv;
        float dsl[16 * 128];
    } sm;
    const int bid = blockIdx.x, tid = threadIdx.x;

    if (bid < 8704) {
        // ---- bf16 convert (A zero-padded to TP rows) ----
        long long gid = ((long long)bid * 256 + tid) * 8;
        const long long ATOT = (long long)NB * TP * ENC;   // 1<<24
        if (gid < ATOT) {
            int n = (int)(gid >> 20);
            int rem = (int)(gid & ((1 << 20) - 1));
            int r = rem >> 9, e = rem & 511;
            uint4 out;
            if (r < TT) {
                const float* s = enc + ((long long)n * TT + r) * ENC + e;
                float4 v0 = *(const float4*)s;
                float4 v1 = *(const float4*)(s + 4);
                out.x = bfpack2(v0.x, v0.y); out.y = bfpack2(v0.z, v0.w);
                out.z = bfpack2(v1.x, v1.y); out.w = bfpack2(v1.z, v1.w);
            } else {
                out.x = out.y = out.z = out.w = 0u;
            }
            *(uint4*)(Abf + gid) = out;
        } else {
            long long j = gid - ATOT;                       // < 2048*512
            const float* s = Wk + j;
            float4 v0 = *(const float4*)s;
            float4 v1 = *(const float4*)(s + 4);
            uint4 out;
            out.x = bfpack2(v0.x, v0.y); out.y = bfpack2(v0.z, v0.w);
            out.z = bfpack2(v1.x, v1.y); out.w = bfpack2(v1.z, v1.w);
            *(uint4*)(Wkbf + j) = out;
        }
    } else if (bid < 8960) {
        // ---- grouped conv1d, register accumulators; writes ftb[t][16] bf16 ----
        int b2 = bid - 8704;
        int tc = b2 & 3, h = (b2 >> 2) & 3, n = b2 >> 4;
        int t0 = tc * 500;
        float* aliW = sm.cv.aliW;
        float* wfT  = sm.cv.wfT;       // [k][c] layout
        float* bfs  = sm.cv.bfs;
        const float* arow = ali_prev + ((long long)n * HH + h) * TT;
        for (int i = tid; i < 632; i += 256) {
            int tt = t0 - KK + i;
            aliW[i] = (tt >= 0 && tt < TT) ? arow[tt] : 0.f;
        }
        for (int i = tid; i < KW * CC; i += 256) {
            int k = i / CC, c = i - k * CC;
            wfT[i] = WF[(h * CC + c) * KW + k];
        }
        if (tid < CC) bfs[tid] = bF[h * CC + tid];
        __syncthreads();
        if (tid < 250) {
            float acc0[CC], acc1[CC];
            #pragma unroll
            for (int c = 0; c < CC; c++) { acc0[c] = 0.f; acc1[c] = 0.f; }
            const int base = 2 * tid;
            float2 w0 = *(const float2*)&aliW[base];
            for (int k = 0; k < 128; k += 2) {
                float2 w2 = *(const float2*)&aliW[base + k + 2];
                #pragma unroll
                for (int cj = 0; cj < 5; cj++) {
                    float2 fk  = *(const float2*)&wfT[k * CC + cj * 2];
                    float2 fk1 = *(const float2*)&wfT[(k + 1) * CC + cj * 2];
                    acc0[2*cj]   += w0.x * fk.x + w0.y * fk1.x;
                    acc0[2*cj+1] += w0.x * fk.y + w0.y * fk1.y;
                    acc1[2*cj]   += w0.y * fk.x + w2.x * fk1.x;
                    acc1[2*cj+1] += w0.y * fk.y + w2.x * fk1.y;
                }
                w0 = w2;
            }
            // tail tap k=128
            #pragma unroll
            for (int cj = 0; cj < 5; cj++) {
                float2 fk = *(const float2*)&wfT[128 * CC + cj * 2];
                acc0[2*cj]   += w0.x * fk.x;  acc0[2*cj+1] += w0.x * fk.y;
                acc1[2*cj]   += w0.y * fk.x;  acc1[2*cj+1] += w0.y * fk.y;
            }
            #pragma unroll
            for (int c = 0; c < CC; c++) { acc0[c] += bfs[c]; acc1[c] += bfs[c]; }
            int t = t0 + base;
            u16* frow = ftb + (((long long)(n * HH + h)) * TP + t) * 16;
            uint4 ra, rb;
            ra.x = bfpack2(acc0[0], acc0[1]); ra.y = bfpack2(acc0[2], acc0[3]);
            ra.z = bfpack2(acc0[4], acc0[5]); ra.w = bfpack2(acc0[6], acc0[7]);
            rb.x = bfpack2(acc0[8], acc0[9]); rb.y = 0u; rb.z = 0u; rb.w = 0u;
            *(uint4*)(frow)     = ra; *(uint4*)(frow + 8)  = rb;
            ra.x = bfpack2(acc1[0], acc1[1]); ra.y = bfpack2(acc1[2], acc1[3]);
            ra.z = bfpack2(acc1[4], acc1[5]); ra.w = bfpack2(acc1[6], acc1[7]);
            rb.x = bfpack2(acc1[8], acc1[9]);
            *(uint4*)(frow + 16) = ra; *(uint4*)(frow + 24) = rb;
        } else if (tc == 3) {
            // zero-pad ftb rows t in [2000, 2048)
            uint4 z = {0u, 0u, 0u, 0u};
            int r0 = 2000 + (tid - 250) * 8;
            u16* frow = ftb + (((long long)(n * HH + h)) * TP + r0) * 16;
            for (int r = 0; r < 8; r++) {
                *(uint4*)(frow + r * 16)     = z;
                *(uint4*)(frow + r * 16 + 8) = z;
            }
        }
    } else if (bid < 8992) {
        // ---- dec_part K-split partials: decp[kc][n][d] ----
        int b2 = bid - 8960;                 // 0..31
        int kc = b2 >> 3, jc = b2 & 7;
        for (int i = tid; i < 2048; i += 256) {
            int nn = i >> 7, kk = i & 127;
            sm.dsl[i] = dec_prev[nn * 512 + kc * 128 + kk];
        }
        __syncthreads();
        int d = jc * 256 + tid;
        float acc[NB];
        #pragma unroll
        for (int n = 0; n < NB; n++) acc[n] = 0.f;
        const float4* w4 = (const float4*)(Wd + (long long)d * 512 + kc * 128);
        for (int e4 = 0; e4 < 32; e4++) {
            float4 w = w4[e4];
            #pragma unroll
            for (int n = 0; n < NB; n++) {
                const float* a = sm.dsl + n * 128 + e4 * 4;
                acc[n] += w.x * a[0] + w.y * a[1] + w.z * a[2] + w.w * a[3];
            }
        }
        #pragma unroll
        for (int n = 0; n < NB; n++) decp[((long long)kc * NB + n) * HATT + d] = acc[n];
    } else {
        // ---- wab[j][16] = Wa[j>>9][j&511][0..9] bf16 (B-ext rows) ----
        int b2 = bid - 8992;                 // 0..3
        int j0 = b2 * 512 + tid * 2;
        #pragma unroll
        for (int q = 0; q < 2; q++) {
            int j = j0 + q;
            int hh = j >> 9, dd = j & 511;
            const float* wr = Wa + ((long long)(hh * ATTD + dd)) * CC;
            uint4 ra, rb;
            ra.x = bfpack2(wr[0], wr[1]); ra.y = bfpack2(wr[2], wr[3]);
            ra.z = bfpack2(wr[4], wr[5]); ra.w = bfpack2(wr[6], wr[7]);
            rb.x = bfpack2(wr[8], wr[9]); rb.y = 0u; rb.z = 0u; rb.w = 0u;
            u16* out = wab + (long long)j * 16;
            *(uint4*)(out)     = ra;
            *(uint4*)(out + 8) = rb;
        }
    }
}

// ---------------- 2. fused GEMM with att folded into K (K = 512 + 32ext) -------
// m97 structure + resident 8KB ext tiles; 40960B LDS -> 4 blocks/CU
__global__ __launch_bounds__(256, 4) void score_gemm_kernel(
    const u16* __restrict__ Abf, const u16* __restrict__ Bbf,
    const u16* __restrict__ ftb, const u16* __restrict__ wab,
    const float* __restrict__ decp, const float* __restrict__ Ww,
    float* __restrict__ score_part)
{
    __shared__ __attribute__((aligned(16))) char smem[40960];
    // [0,16384) lA | [16384,32768) lB | [32768,36864) extA | [36864,40960) extB
    float* sred = (float*)smem;      // reused after final barrier

    const int bid = blockIdx.x;
    const int swz = (bid & 7) * 512 + (bid >> 3);   // T1: contiguous chunk per XCD
    const int nt = swz & 15, mt = (swz >> 4) & 15, n = swz >> 8;
    const int tid = threadIdx.x, wave = tid >> 6, lane = tid & 63;
    const int l16 = lane & 15, lk = lane >> 4;
    const int h = nt >> 2;

    const u16* Aptr = Abf + ((long long)n * TP + mt * 128) * ENC;
    const u16* Bptr = Bbf + (long long)nt * 128 * ENC;

    f32x4 acc[4][4];
    #pragma unroll
    for (int mi = 0; mi < 4; mi++)
        #pragma unroll
        for (int nj = 0; nj < 4; nj++) {
            f32x4 z = {0.f, 0.f, 0.f, 0.f};
            acc[mi][nj] = z;
        }

    const int wrow = (wave >> 1) * 64, wcol = (wave & 1) * 64;
    const int t0 = mt * 128, dd0 = (nt & 3) * 128;

    // ---- stage resident ext tiles (4KB each, linear 1:1 copies) ----
    {
        const char* eAsrc = (const char*)(ftb + (((long long)(n * HH + h)) * TP + t0) * 16);
        const char* eBsrc = (const char*)(wab + (long long)nt * 128 * 16);
        __builtin_amdgcn_global_load_lds(
            (const AS1 void*)(eAsrc + tid * 16),
            (AS3 void*)(smem + 32768 + wave * 1024), 16, 0, 0);
        __builtin_amdgcn_global_load_lds(
            (const AS1 void*)(eBsrc + tid * 16),
            (AS3 void*)(smem + 36864 + wave * 1024), 16, 0, 0);
    }

    // ---- main K loop: linear LDS dest, inverse-swizzled source (rule #21) ----
    for (int kt = 0; kt < 8; kt++) {
        const int k0 = kt * 64;
        #pragma unroll
        for (int i = 0; i < 4; i++) {
            int b = i * 4096 + tid * 16;
            int r = b >> 7, kb = b & 127;
            int kbs = kb ^ ((r & 7) << 4);
            __builtin_amdgcn_global_load_lds(
                (const AS1 void*)(Aptr + r * ENC + k0 + (kbs >> 1)),
                (AS3 void*)(smem + i * 4096 + wave * 1024), 16, 0, 0);
            __builtin_amdgcn_global_load_lds(
                (const AS1 void*)(Bptr + r * ENC + k0 + (kbs >> 1)),
                (AS3 void*)(smem + 16384 + i * 4096 + wave * 1024), 16, 0, 0);
        }
        __syncthreads();    // drains vmcnt(0): tiles resident
        #pragma unroll
        for (int ks = 0; ks < 64; ks += 32) {
            bf16x8 af[4], bf[4];
            #pragma unroll
            for (int mi = 0; mi < 4; mi++) {
                int row = wrow + mi * 16 + l16;
                int cb = (ks * 2 + lk * 16) ^ ((row & 7) << 4);
                af[mi] = *(const bf16x8*)(smem + row * 128 + cb);
            }
            #pragma unroll
            for (int nj = 0; nj < 4; nj++) {
                int row = wcol + nj * 16 + l16;
                int cb = (ks * 2 + lk * 16) ^ ((row & 7) << 4);
                bf[nj] = *(const bf16x8*)(smem + 16384 + row * 128 + cb);
            }
            #pragma unroll
            for (int mi = 0; mi < 4; mi++)
                #pragma unroll
                for (int nj = 0; nj < 4; nj++)
                    acc[mi][nj] = __builtin_amdgcn_mfma_f32_16x16x32_bf16(
                        af[mi], bf[nj], acc[mi][nj], 0, 0, 0);
        }
        __syncthreads();    // all reads done before next stage overwrites
    }

    // ---- K-extension step: att fold (c 0..9 valid, upper K zero) ----
    {
        const u16* eA = (const u16*)(smem + 32768);
        const u16* eB = (const u16*)(smem + 36864);
        bf16x8 zer = {0, 0, 0, 0, 0, 0, 0, 0};
        bf16x8 af[4], bf[4];
        #pragma unroll
        for (int mi = 0; mi < 4; mi++) {
            af[mi] = zer;
            if (lk < 2) af[mi] = *(const bf16x8*)(eA + (wrow + mi * 16 + l16) * 16 + lk * 8);
        }
        #pragma unroll
        for (int nj = 0; nj < 4; nj++) {
            bf[nj] = zer;
            if (lk < 2) bf[nj] = *(const bf16x8*)(eB + (wcol + nj * 16 + l16) * 16 + lk * 8);
        }
        #pragma unroll
        for (int mi = 0; mi < 4; mi++)
            #pragma unroll
            for (int nj = 0; nj < 4; nj++)
                acc[mi][nj] = __builtin_amdgcn_mfma_f32_16x16x32_bf16(
                    af[mi], bf[nj], acc[mi][nj], 0, 0, 0);
    }

    // ---- epilogue: score'= sum_d -2*ww*rcp(exp(2v)+1)  (shift cancels in softmax)
    float wm2[4], dec4[4];
    #pragma unroll
    for (int nj = 0; nj < 4; nj++) {
        int cl = wcol + nj * 16 + l16;
        wm2[nj] = -2.f * Ww[h * ATTD + dd0 + cl];
        int j = nt * 128 + cl;
        dec4[nj] = decp[((long long)0 * NB + n) * HATT + j]
                 + decp[((long long)1 * NB + n) * HATT + j]
                 + decp[((long long)2 * NB + n) * HATT + j]
                 + decp[((long long)3 * NB + n) * HATT + j];
    }

    #pragma unroll
    for (int mi = 0; mi < 4; mi++) {
        #pragma unroll
        for (int j = 0; j < 4; j++) {
            int rl = wrow + mi * 16 + lk * 4 + j;
            float s = 0.f;
            #pragma unroll
            for (int nj = 0; nj < 4; nj++) {
                float v = acc[mi][nj][j] + dec4[nj];
                float e = __expf(v + v);
                s = fmaf(wm2[nj], __builtin_amdgcn_rcpf(e + 1.f), s);
            }
            s += __shfl_xor(s, 1); s += __shfl_xor(s, 2);
            s += __shfl_xor(s, 4); s += __shfl_xor(s, 8);
            if (l16 == 0) sred[(wave & 1) * 128 + rl] = s;
        }
    }
    __syncthreads();
    if (tid < 128) {
        int t = t0 + tid;
        if (t < TT)
            score_part[((long long)((nt & 3) * NB + n) * HH + h) * TT + t] =
                sred[tid] + sred[128 + tid];
    }
}

// ---------------- 3. masked softmax over t (sums the 4 partial slices) ---------
__global__ __launch_bounds__(256) void softmax_kernel(
    const float* __restrict__ score_part, const int* __restrict__ enc_len,
    float* __restrict__ ali)
{
    int n = blockIdx.x >> 2, h = blockIdx.x & 3;
    int len = enc_len[n];
    int tid = threadIdx.x;
    float s[8];
    float lmax = -3.4e38f;
    #pragma unroll
    for (int i = 0; i < 8; i++) {
        int t = tid + i * 256;
        float v = -3.4e38f;
        if (t < len) {
            v = 0.f;
            #pragma unroll
            for (int q = 0; q < 4; q++)
                v += score_part[((long long)(q * NB + n) * HH + h) * TT + t];
        }
        s[i] = v;
        lmax = fmaxf(lmax, v);
    }
    __shared__ float red[256];
    red[tid] = lmax; __syncthreads();
    for (int off = 128; off; off >>= 1) {
        if (tid < off) red[tid] = fmaxf(red[tid], red[tid + off]);
        __syncthreads();
    }
    float bmax = red[0];
    __syncthreads();
    float lsum = 0.f;
    #pragma unroll
    for (int i = 0; i < 8; i++) {
        int t = tid + i * 256;
        if (t < len) { s[i] = expf(s[i] - bmax); lsum += s[i]; }
        else s[i] = 0.f;
    }
    red[tid] = lsum; __syncthreads();
    for (int off = 128; off; off >>= 1) {
        if (tid < off) red[tid] += red[tid + off];
        __syncthreads();
    }
    float inv = 1.f / red[0];
    float* arow = ali + ((long long)n * HH + h) * TT;
    #pragma unroll
    for (int i = 0; i < 8; i++) {
        int t = tid + i * 256;
        if (t < TT) arow[t] = s[i] * inv;
    }
}

// ---------------- 4. a_enc partials from bf16 Abf (grid 512 = n x 32 chunks) ---
__global__ __launch_bounds__(256) void a_enc_kernel(
    const float* __restrict__ ali, const u16* __restrict__ Abf,
    const int* __restrict__ enc_len, float* __restrict__ a_enc_part)
{
    int tc = blockIdx.x & 31, n = blockIdx.x >> 5;
    int tid = threadIdx.x;
    int len = enc_len[n];
    int tbeg = tc * 63;
    int cnt = len - tbeg; if (cnt > 63) cnt = 63; if (cnt < 0) cnt = 0;
    float acc[HH][2];
    #pragma unroll
    for (int hh = 0; hh < HH; hh++) { acc[hh][0] = 0.f; acc[hh][1] = 0.f; }
    for (int tt = 0; tt < cnt; tt++) {
        int t = tbeg + tt;
        float w0 = ali[((long long)n * HH + 0) * TT + t];
        float w1 = ali[((long long)n * HH + 1) * TT + t];
        float w2 = ali[((long long)n * HH + 2) * TT + t];
        float w3 = ali[((long long)n * HH + 3) * TT + t];
        unsigned u = *(const unsigned*)(Abf + ((long long)n * TP + t) * ENC + tid * 2);
        float ex = __builtin_bit_cast(float, u << 16);
        float ey = __builtin_bit_cast(float, u & 0xffff0000u);
        acc[0][0] += w0 * ex; acc[0][1] += w0 * ey;
        acc[1][0] += w1 * ex; acc[1][1] += w1 * ey;
        acc[2][0] += w2 * ex; acc[2][1] += w2 * ey;
        acc[3][0] += w3 * ex; acc[3][1] += w3 * ey;
    }
    #pragma unroll
    for (int hh = 0; hh < HH; hh++) {
        a_enc_part[(((long long)tc * NB + n) * HH + hh) * ENC + tid * 2 + 0] = acc[hh][0];
        a_enc_part[(((long long)tc * NB + n) * HH + hh) * ENC + tid * 2 + 1] = acc[hh][1];
    }
}

// ---------------- 5. ctx_tmp partials (K-split, grid 32) -----------------------
__global__ __launch_bounds__(256) void ctx_tmp_kernel(
    const float* __restrict__ a_enc_part, const float* __restrict__ We,
    const float* __restrict__ be, float* __restrict__ ctmp)
{
    int kc = blockIdx.x >> 3, jc = blockIdx.x & 7;
    int tid = threadIdx.x;
    int j = jc * 256 + tid;
    int h = j >> 9;                       // uniform per block
    __shared__ float aes[16 * 128];
    for (int i = tid; i < 2048; i += 256) {
        int nn = i >> 7, kk = i & 127;
        float s = 0.f;
        for (int tc = 0; tc < 32; tc++)
            s += a_enc_part[(((long long)tc * NB + nn) * HH + h) * ENC + kc * 128 + kk];
        aes[i] = s;
    }
    __syncthreads();
    float acc[NB];
    #pragma unroll
    for (int n = 0; n < NB; n++) acc[n] = 0.f;
    const float4* w4 = (const float4*)(We + (long long)j * 512 + kc * 128);
    for (int e4 = 0; e4 < 32; e4++) {
        float4 w = w4[e4];
        #pragma unroll
        for (int n = 0; n < NB; n++) {
            const float* a = aes + n * 128 + e4 * 4;
            acc[n] += w.x * a[0] + w.y * a[1] + w.z * a[2] + w.w * a[3];
        }
    }
    float bias = (kc == 0) ? be[j] : 0.f;
    #pragma unroll
    for (int n = 0; n < NB; n++)
        ctmp[((long long)kc * NB + n) * HATT + j] = acc[n] + bias;
}

// ---------------- 6. ctx_out (grid 16 = 8 eo-chunks x 2 n-chunks) --------------
__global__ __launch_bounds__(256) void ctx_out_kernel(
    const float* __restrict__ ctmp, const float* __restrict__ Wc,
    const float* __restrict__ bc, float* __restrict__ out_ctx)
{
    int ec = blockIdx.x & 7, nc = blockIdx.x >> 3;
    int tid = threadIdx.x;
    __shared__ float ct[8 * 2048];        // 64 KB: ct[nn][j], nn = local n
    __shared__ float red[4][64][8];       // 8 KB
    for (int i = tid; i < 8 * 2048; i += 256) {
        int nn = i >> 11, j = i & 2047;
        int n = nc * 8 + nn;
        ct[i] = ctmp[((long long)0 * NB + n) * HATT + j]
              + ctmp[((long long)1 * NB + n) * HATT + j]
              + ctmp[((long long)2 * NB + n) * HATT + j]
              + ctmp[((long long)3 * NB + n) * HATT + j];
    }
    __syncthreads();
    int eo = tid & 63, kq = tid >> 6;     // 64 eo x 4 K-quarters
    int eg = ec * 64 + eo;
    float acc[8];
    #pragma unroll
    for (int nn = 0; nn < 8; nn++) acc[nn] = 0.f;
    const float4* w4 = (const float4*)(Wc + (long long)eg * HATT + kq * 512);
    for (int j4 = 0; j4 < 128; j4++) {
        float4 w = w4[j4];
        #pragma unroll
        for (int nn = 0; nn < 8; nn++) {
            const float* a = ct + nn * 2048 + kq * 512 + j4 * 4;
            acc[nn] += w.x * a[0] + w.y * a[1] + w.z * a[2] + w.w * a[3];
        }
    }
    #pragma unroll
    for (int nn = 0; nn < 8; nn++) red[kq][eo][nn] = acc[nn];
    __syncthreads();
    #pragma unroll
    for (int r = 0; r < 2; r++) {
        int idx = tid + r * 256;
        int eo2 = idx & 63, nn2 = idx >> 6;   // nn2 0..7
        float s = red[0][eo2][nn2] + red[1][eo2][nn2]
                + red[2][eo2][nn2] + red[3][eo2][nn2];
        out_ctx[((long long)(nc * 8 + nn2)) * 512 + ec * 64 + eo2] = s + bc[ec * 64 + eo2];
    }
}

// ---------------- launch ----------------
extern "C" void kernel_launch(void* const* d_in, const int* in_sizes, int n_in,
                              void* d_out, int out_size, void* d_ws, size_t ws_size,
                              hipStream_t stream)
{
    (void)in_sizes; (void)n_in; (void)out_size; (void)ws_size;
    const float* enc_pad  = (const float*)d_in[0];
    const int*   enc_len  = (const int*)  d_in[1];
    const float* dec_prev = (const float*)d_in[2];
    const float* ali_prev = (const float*)d_in[3];
    const float* We = (const float*)d_in[4];
    const float* be = (const float*)d_in[5];
    const float* Wk = (const float*)d_in[6];
    const float* Wd = (const float*)d_in[7];
    const float* WF = (const float*)d_in[8];
    const float* bF = (const float*)d_in[9];
    const float* Wa = (const float*)d_in[10];
    const float* Ww = (const float*)d_in[11];
    const float* Wc = (const float*)d_in[12];
    const float* bc = (const float*)d_in[13];

    char* ws = (char*)d_ws;
    u16*   Abf  = (u16*)  (ws);                 // 33,554,432 B
    u16*   Wkbf = (u16*)  (ws + 33554432);      //  2,097,152 B
    u16*   ftb  = (u16*)  (ws + 35651584);      //  4,194,304 B  [n*h][2048][16]
    u16*   wab  = (u16*)  (ws + 39845888);      //     65,536 B  [2048][16]
    float* decp = (float*)(ws + 39911424);      //    524,288 B  [4][16][2048]
    float* spart= (float*)(ws + 40435712);      //  2,048,000 B
    float* aep  = (float*)(ws + 40435712);      // alias spart region (4 MB, dead after softmax)
    float* ctmp = (float*)(ws + 39911424);      // alias decp (dead after gemm)
    // high-water: 40,435,712 + 4,194,304 = 44,630,016 B (within proven envelope)

    float* ali = (float*)d_out;                 // [16][4][2000]
    float* ctx = (float*)d_out + NB * HH * TT;  // [16][512]

    prep_kernel      <<<8996, 256, 0, stream>>>(enc_pad, Wk, ali_prev, WF, bF,
                                                dec_prev, Wd, Wa,
                                                Abf, Wkbf, ftb, wab, decp);
    score_gemm_kernel<<<4096, 256, 0, stream>>>(Abf, Wkbf, ftb, wab, decp, Ww, spart);
    softmax_kernel   <<<64,   256, 0, stream>>>(spart, enc_len, ali);
    a_enc_kernel     <<<512,  256, 0, stream>>>(ali, Abf, enc_len, aep);
    ctx_tmp_kernel   <<<32,   256, 0, stream>>>(aep, We, be, ctmp);
    ctx_out_kernel   <<<16,   256, 0, stream>>>(ctmp, Wc, bc, ctx);
}

// Round 7
// 191.781 us; speedup vs baseline: 2.6389x; 1.0909x over previous
//
#include <hip/hip_runtime.h>

// ---------------- problem dims ----------------
#define NB   16
#define TT   2000
#define TP   2048      // padded T for GEMM tiling
#define ENC  512
#define ATTD 512
#define HH   4
#define CC   10
#define KK   64        // conv half-window
#define KW   129       // 2K+1
#define HATT 2048

typedef unsigned short u16;
typedef __attribute__((ext_vector_type(8))) short bf16x8;
typedef __attribute__((ext_vector_type(4))) float f32x4;

#define AS1 __attribute__((address_space(1)))
#define AS3 __attribute__((address_space(3)))

// round-to-nearest-even f32 -> bf16, packed pair
__device__ inline unsigned bfpack2(float lo, float hi) {
    unsigned a = __builtin_bit_cast(unsigned, lo);
    unsigned b = __builtin_bit_cast(unsigned, hi);
    a = (a + 0x7fffu + ((a >> 16) & 1u)) >> 16;
    b = (b + 0x7fffu + ((b >> 16) & 1u)) >> 16;
    return a | (b << 16);
}

// ---------------- 1. fused prep: convert + conv_f(->bf16 f^T) + dec + Wa pack --
// blocks [0,8704): bf16 convert; [8704,8960): conv1d; [8960,8992): dec partials;
// [8992,8996): Wa -> wab pack
__global__ __launch_bounds__(256) void prep_kernel(
    const float* __restrict__ enc, const float* __restrict__ Wk,
    const float* __restrict__ ali_prev, const float* __restrict__ WF,
    const float* __restrict__ bF, const float* __restrict__ dec_prev,
    const float* __restrict__ Wd, const float* __restrict__ Wa,
    u16* __restrict__ Abf, u16* __restrict__ Wkbf,
    u16* __restrict__ ftb, u16* __restrict__ wab,
    float* __restrict__ decp)
{
    __shared__ union {
        struct { float aliW[632]; float wfT[KW * CC]; float bfs[CC]; } cv;
        float dsl[16 * 128];
    } sm;
    const int bid = blockIdx.x, tid = threadIdx.x;

    if (bid < 8704) {
        // ---- bf16 convert (A zero-padded to TP rows) ----
        long long gid = ((long long)bid * 256 + tid) * 8;
        const long long ATOT = (long long)NB * TP * ENC;   // 1<<24
        if (gid < ATOT) {
            int n = (int)(gid >> 20);
            int rem = (int)(gid & ((1 << 20) - 1));
            int r = rem >> 9, e = rem & 511;
            uint4 out;
            if (r < TT) {
                const float* s = enc + ((long long)n * TT + r) * ENC + e;
                float4 v0 = *(const float4*)s;
                float4 v1 = *(const float4*)(s + 4);
                out.x = bfpack2(v0.x, v0.y); out.y = bfpack2(v0.z, v0.w);
                out.z = bfpack2(v1.x, v1.y); out.w = bfpack2(v1.z, v1.w);
            } else {
                out.x = out.y = out.z = out.w = 0u;
            }
            *(uint4*)(Abf + gid) = out;
        } else {
            long long j = gid - ATOT;                       // < 2048*512
            const float* s = Wk + j;
            float4 v0 = *(const float4*)s;
            float4 v1 = *(const float4*)(s + 4);
            uint4 out;
            out.x = bfpack2(v0.x, v0.y); out.y = bfpack2(v0.z, v0.w);
            out.z = bfpack2(v1.x, v1.y); out.w = bfpack2(v1.z, v1.w);
            *(uint4*)(Wkbf + j) = out;
        }
    } else if (bid < 8960) {
        // ---- grouped conv1d, register accumulators; writes ftb[t][16] bf16 ----
        int b2 = bid - 8704;
        int tc = b2 & 3, h = (b2 >> 2) & 3, n = b2 >> 4;
        int t0 = tc * 500;
        float* aliW = sm.cv.aliW;
        float* wfT  = sm.cv.wfT;       // [k][c] layout
        float* bfs  = sm.cv.bfs;
        const float* arow = ali_prev + ((long long)n * HH + h) * TT;
        for (int i = tid; i < 632; i += 256) {
            int tt = t0 - KK + i;
            aliW[i] = (tt >= 0 && tt < TT) ? arow[tt] : 0.f;
        }
        for (int i = tid; i < KW * CC; i += 256) {
            int k = i / CC, c = i - k * CC;
            wfT[i] = WF[(h * CC + c) * KW + k];
        }
        if (tid < CC) bfs[tid] = bF[h * CC + tid];
        __syncthreads();
        if (tid < 250) {
            float acc0[CC], acc1[CC];
            #pragma unroll
            for (int c = 0; c < CC; c++) { acc0[c] = 0.f; acc1[c] = 0.f; }
            const int base = 2 * tid;
            float2 w0 = *(const float2*)&aliW[base];
            for (int k = 0; k < 128; k += 2) {
                float2 w2 = *(const float2*)&aliW[base + k + 2];
                #pragma unroll
                for (int cj = 0; cj < 5; cj++) {
                    float2 fk  = *(const float2*)&wfT[k * CC + cj * 2];
                    float2 fk1 = *(const float2*)&wfT[(k + 1) * CC + cj * 2];
                    acc0[2*cj]   += w0.x * fk.x + w0.y * fk1.x;
                    acc0[2*cj+1] += w0.x * fk.y + w0.y * fk1.y;
                    acc1[2*cj]   += w0.y * fk.x + w2.x * fk1.x;
                    acc1[2*cj+1] += w0.y * fk.y + w2.x * fk1.y;
                }
                w0 = w2;
            }
            // tail tap k=128
            #pragma unroll
            for (int cj = 0; cj < 5; cj++) {
                float2 fk = *(const float2*)&wfT[128 * CC + cj * 2];
                acc0[2*cj]   += w0.x * fk.x;  acc0[2*cj+1] += w0.x * fk.y;
                acc1[2*cj]   += w0.y * fk.x;  acc1[2*cj+1] += w0.y * fk.y;
            }
            #pragma unroll
            for (int c = 0; c < CC; c++) { acc0[c] += bfs[c]; acc1[c] += bfs[c]; }
            int t = t0 + base;
            u16* frow = ftb + (((long long)(n * HH + h)) * TP + t) * 16;
            uint4 ra, rb;
            ra.x = bfpack2(acc0[0], acc0[1]); ra.y = bfpack2(acc0[2], acc0[3]);
            ra.z = bfpack2(acc0[4], acc0[5]); ra.w = bfpack2(acc0[6], acc0[7]);
            rb.x = bfpack2(acc0[8], acc0[9]); rb.y = 0u; rb.z = 0u; rb.w = 0u;
            *(uint4*)(frow)     = ra; *(uint4*)(frow + 8)  = rb;
            ra.x = bfpack2(acc1[0], acc1[1]); ra.y = bfpack2(acc1[2], acc1[3]);
            ra.z = bfpack2(acc1[4], acc1[5]); ra.w = bfpack2(acc1[6], acc1[7]);
            rb.x = bfpack2(acc1[8], acc1[9]);
            *(uint4*)(frow + 16) = ra; *(uint4*)(frow + 24) = rb;
        } else if (tc == 3) {
            // zero-pad ftb rows t in [2000, 2048)
            uint4 z = {0u, 0u, 0u, 0u};
            int r0 = 2000 + (tid - 250) * 8;
            u16* frow = ftb + (((long long)(n * HH + h)) * TP + r0) * 16;
            for (int r = 0; r < 8; r++) {
                *(uint4*)(frow + r * 16)     = z;
                *(uint4*)(frow + r * 16 + 8) = z;
            }
        }
    } else if (bid < 8992) {
        // ---- dec_part K-split partials: decp[kc][n][d] ----
        int b2 = bid - 8960;                 // 0..31
        int kc = b2 >> 3, jc = b2 & 7;
        for (int i = tid; i < 2048; i += 256) {
            int nn = i >> 7, kk = i & 127;
            sm.dsl[i] = dec_prev[nn * 512 + kc * 128 + kk];
        }
        __syncthreads();
        int d = jc * 256 + tid;
        float acc[NB];
        #pragma unroll
        for (int n = 0; n < NB; n++) acc[n] = 0.f;
        const float4* w4 = (const float4*)(Wd + (long long)d * 512 + kc * 128);
        for (int e4 = 0; e4 < 32; e4++) {
            float4 w = w4[e4];
            #pragma unroll
            for (int n = 0; n < NB; n++) {
                const float* a = sm.dsl + n * 128 + e4 * 4;
                acc[n] += w.x * a[0] + w.y * a[1] + w.z * a[2] + w.w * a[3];
            }
        }
        #pragma unroll
        for (int n = 0; n < NB; n++) decp[((long long)kc * NB + n) * HATT + d] = acc[n];
    } else {
        // ---- wab[j][16] = Wa[j>>9][j&511][0..9] bf16 (B-ext rows) ----
        int b2 = bid - 8992;                 // 0..3
        int j0 = b2 * 512 + tid * 2;
        #pragma unroll
        for (int q = 0; q < 2; q++) {
            int j = j0 + q;
            int hh = j >> 9, dd = j & 511;
            const float* wr = Wa + ((long long)(hh * ATTD + dd)) * CC;
            uint4 ra, rb;
            ra.x = bfpack2(wr[0], wr[1]); ra.y = bfpack2(wr[2], wr[3]);
            ra.z = bfpack2(wr[4], wr[5]); ra.w = bfpack2(wr[6], wr[7]);
            rb.x = bfpack2(wr[8], wr[9]); rb.y = 0u; rb.z = 0u; rb.w = 0u;
            u16* out = wab + (long long)j * 16;
            *(uint4*)(out)     = ra;
            *(uint4*)(out + 8) = rb;
        }
    }
}

// ---------------- 2. fused GEMM with att folded into K (K = 512 + 32ext) -------
// m97 structure + resident 8KB ext tiles; early-exit M-tiles past enc_len
__global__ __launch_bounds__(256, 4) void score_gemm_kernel(
    const u16* __restrict__ Abf, const u16* __restrict__ Bbf,
    const u16* __restrict__ ftb, const u16* __restrict__ wab,
    const float* __restrict__ decp, const float* __restrict__ Ww,
    const int* __restrict__ enc_len, float* __restrict__ score_part)
{
    __shared__ __attribute__((aligned(16))) char smem[40960];
    // [0,16384) lA | [16384,32768) lB | [32768,36864) extA | [36864,40960) extB
    float* sred = (float*)smem;      // reused after final barrier

    const int bid = blockIdx.x;
    const int swz = (bid & 7) * 512 + (bid >> 3);   // T1: contiguous chunk per XCD
    const int nt = swz & 15, mt = (swz >> 4) & 15, n = swz >> 8;

    // rows t in [mt*128, mt*128+128) all masked by softmax -> skip entirely
    if (mt * 128 >= enc_len[n]) return;

    const int tid = threadIdx.x, wave = tid >> 6, lane = tid & 63;
    const int l16 = lane & 15, lk = lane >> 4;
    const int h = nt >> 2;

    const u16* Aptr = Abf + ((long long)n * TP + mt * 128) * ENC;
    const u16* Bptr = Bbf + (long long)nt * 128 * ENC;

    f32x4 acc[4][4];
    #pragma unroll
    for (int mi = 0; mi < 4; mi++)
        #pragma unroll
        for (int nj = 0; nj < 4; nj++) {
            f32x4 z = {0.f, 0.f, 0.f, 0.f};
            acc[mi][nj] = z;
        }

    const int wrow = (wave >> 1) * 64, wcol = (wave & 1) * 64;
    const int t0 = mt * 128, dd0 = (nt & 3) * 128;

    // ---- stage resident ext tiles (4KB each, linear 1:1 copies) ----
    {
        const char* eAsrc = (const char*)(ftb + (((long long)(n * HH + h)) * TP + t0) * 16);
        const char* eBsrc = (const char*)(wab + (long long)nt * 128 * 16);
        __builtin_amdgcn_global_load_lds(
            (const AS1 void*)(eAsrc + tid * 16),
            (AS3 void*)(smem + 32768 + wave * 1024), 16, 0, 0);
        __builtin_amdgcn_global_load_lds(
            (const AS1 void*)(eBsrc + tid * 16),
            (AS3 void*)(smem + 36864 + wave * 1024), 16, 0, 0);
    }

    // ---- main K loop: linear LDS dest, inverse-swizzled source (rule #21) ----
    for (int kt = 0; kt < 8; kt++) {
        const int k0 = kt * 64;
        #pragma unroll
        for (int i = 0; i < 4; i++) {
            int b = i * 4096 + tid * 16;
            int r = b >> 7, kb = b & 127;
            int kbs = kb ^ ((r & 7) << 4);
            __builtin_amdgcn_global_load_lds(
                (const AS1 void*)(Aptr + r * ENC + k0 + (kbs >> 1)),
                (AS3 void*)(smem + i * 4096 + wave * 1024), 16, 0, 0);
            __builtin_amdgcn_global_load_lds(
                (const AS1 void*)(Bptr + r * ENC + k0 + (kbs >> 1)),
                (AS3 void*)(smem + 16384 + i * 4096 + wave * 1024), 16, 0, 0);
        }
        __syncthreads();    // drains vmcnt(0): tiles resident
        #pragma unroll
        for (int ks = 0; ks < 64; ks += 32) {
            bf16x8 af[4], bf[4];
            #pragma unroll
            for (int mi = 0; mi < 4; mi++) {
                int row = wrow + mi * 16 + l16;
                int cb = (ks * 2 + lk * 16) ^ ((row & 7) << 4);
                af[mi] = *(const bf16x8*)(smem + row * 128 + cb);
            }
            #pragma unroll
            for (int nj = 0; nj < 4; nj++) {
                int row = wcol + nj * 16 + l16;
                int cb = (ks * 2 + lk * 16) ^ ((row & 7) << 4);
                bf[nj] = *(const bf16x8*)(smem + 16384 + row * 128 + cb);
            }
            #pragma unroll
            for (int mi = 0; mi < 4; mi++)
                #pragma unroll
                for (int nj = 0; nj < 4; nj++)
                    acc[mi][nj] = __builtin_amdgcn_mfma_f32_16x16x32_bf16(
                        af[mi], bf[nj], acc[mi][nj], 0, 0, 0);
        }
        __syncthreads();    // all reads done before next stage overwrites
    }

    // ---- K-extension step: att fold (c 0..9 valid, upper K zero) ----
    {
        const u16* eA = (const u16*)(smem + 32768);
        const u16* eB = (const u16*)(smem + 36864);
        bf16x8 zer = {0, 0, 0, 0, 0, 0, 0, 0};
        bf16x8 af[4], bf[4];
        #pragma unroll
        for (int mi = 0; mi < 4; mi++) {
            af[mi] = zer;
            if (lk < 2) af[mi] = *(const bf16x8*)(eA + (wrow + mi * 16 + l16) * 16 + lk * 8);
        }
        #pragma unroll
        for (int nj = 0; nj < 4; nj++) {
            bf[nj] = zer;
            if (lk < 2) bf[nj] = *(const bf16x8*)(eB + (wcol + nj * 16 + l16) * 16 + lk * 8);
        }
        #pragma unroll
        for (int mi = 0; mi < 4; mi++)
            #pragma unroll
            for (int nj = 0; nj < 4; nj++)
                acc[mi][nj] = __builtin_amdgcn_mfma_f32_16x16x32_bf16(
                    af[mi], bf[nj], acc[mi][nj], 0, 0, 0);
    }

    // ---- epilogue: score'= sum_d -2*ww*rcp(exp(2v)+1)  (shift cancels in softmax)
    float wm2[4], dec4[4];
    #pragma unroll
    for (int nj = 0; nj < 4; nj++) {
        int cl = wcol + nj * 16 + l16;
        wm2[nj] = -2.f * Ww[h * ATTD + dd0 + cl];
        int j = nt * 128 + cl;
        dec4[nj] = decp[((long long)0 * NB + n) * HATT + j]
                 + decp[((long long)1 * NB + n) * HATT + j]
                 + decp[((long long)2 * NB + n) * HATT + j]
                 + decp[((long long)3 * NB + n) * HATT + j];
    }

    #pragma unroll
    for (int mi = 0; mi < 4; mi++) {
        #pragma unroll
        for (int j = 0; j < 4; j++) {
            int rl = wrow + mi * 16 + lk * 4 + j;
            float s = 0.f;
            #pragma unroll
            for (int nj = 0; nj < 4; nj++) {
                float v = acc[mi][nj][j] + dec4[nj];
                float e = __expf(v + v);
                s = fmaf(wm2[nj], __builtin_amdgcn_rcpf(e + 1.f), s);
            }
            s += __shfl_xor(s, 1); s += __shfl_xor(s, 2);
            s += __shfl_xor(s, 4); s += __shfl_xor(s, 8);
            if (l16 == 0) sred[(wave & 1) * 128 + rl] = s;
        }
    }
    __syncthreads();
    if (tid < 128) {
        int t = t0 + tid;
        if (t < TT)
            score_part[((long long)((nt & 3) * NB + n) * HH + h) * TT + t] =
                sred[tid] + sred[128 + tid];
    }
}

// ---------------- 3. masked softmax over t (sums the 4 partial slices) ---------
__global__ __launch_bounds__(256) void softmax_kernel(
    const float* __restrict__ score_part, const int* __restrict__ enc_len,
    float* __restrict__ ali)
{
    int n = blockIdx.x >> 2, h = blockIdx.x & 3;
    int len = enc_len[n];
    int tid = threadIdx.x;
    float s[8];
    float lmax = -3.4e38f;
    #pragma unroll
    for (int i = 0; i < 8; i++) {
        int t = tid + i * 256;
        float v = -3.4e38f;
        if (t < len) {
            v = 0.f;
            #pragma unroll
            for (int q = 0; q < 4; q++)
                v += score_part[((long long)(q * NB + n) * HH + h) * TT + t];
        }
        s[i] = v;
        lmax = fmaxf(lmax, v);
    }
    __shared__ float red[256];
    red[tid] = lmax; __syncthreads();
    for (int off = 128; off; off >>= 1) {
        if (tid < off) red[tid] = fmaxf(red[tid], red[tid + off]);
        __syncthreads();
    }
    float bmax = red[0];
    __syncthreads();
    float lsum = 0.f;
    #pragma unroll
    for (int i = 0; i < 8; i++) {
        int t = tid + i * 256;
        if (t < len) { s[i] = expf(s[i] - bmax); lsum += s[i]; }
        else s[i] = 0.f;
    }
    red[tid] = lsum; __syncthreads();
    for (int off = 128; off; off >>= 1) {
        if (tid < off) red[tid] += red[tid + off];
        __syncthreads();
    }
    float inv = 1.f / red[0];
    float* arow = ali + ((long long)n * HH + h) * TT;
    #pragma unroll
    for (int i = 0; i < 8; i++) {
        int t = tid + i * 256;
        if (t < TT) arow[t] = s[i] * inv;
    }
}

// ---------------- 4. a_enc partials from bf16 Abf (grid 512 = n x 32 chunks) ---
__global__ __launch_bounds__(256) void a_enc_kernel(
    const float* __restrict__ ali, const u16* __restrict__ Abf,
    const int* __restrict__ enc_len, float* __restrict__ a_enc_part)
{
    int tc = blockIdx.x & 31, n = blockIdx.x >> 5;
    int tid = threadIdx.x;
    int len = enc_len[n];
    int tbeg = tc * 63;
    int cnt = len - tbeg; if (cnt > 63) cnt = 63; if (cnt < 0) cnt = 0;
    __shared__ float aliS[HH][64];
    {
        int hh = tid >> 6, tt = tid & 63;   // 256 threads cover 4x64 exactly
        aliS[hh][tt] = (tt < cnt) ? ali[((long long)n * HH + hh) * TT + tbeg + tt] : 0.f;
    }
    __syncthreads();
    float acc[HH][2];
    #pragma unroll
    for (int hh = 0; hh < HH; hh++) { acc[hh][0] = 0.f; acc[hh][1] = 0.f; }
    #pragma unroll 4
    for (int tt = 0; tt < cnt; tt++) {
        int t = tbeg + tt;
        float w0 = aliS[0][tt], w1 = aliS[1][tt], w2 = aliS[2][tt], w3 = aliS[3][tt];
        unsigned u = *(const unsigned*)(Abf + ((long long)n * TP + t) * ENC + tid * 2);
        float ex = __builtin_bit_cast(float, u << 16);
        float ey = __builtin_bit_cast(float, u & 0xffff0000u);
        acc[0][0] += w0 * ex; acc[0][1] += w0 * ey;
        acc[1][0] += w1 * ex; acc[1][1] += w1 * ey;
        acc[2][0] += w2 * ex; acc[2][1] += w2 * ey;
        acc[3][0] += w3 * ex; acc[3][1] += w3 * ey;
    }
    #pragma unroll
    for (int hh = 0; hh < HH; hh++) {
        a_enc_part[(((long long)tc * NB + n) * HH + hh) * ENC + tid * 2 + 0] = acc[hh][0];
        a_enc_part[(((long long)tc * NB + n) * HH + hh) * ENC + tid * 2 + 1] = acc[hh][1];
    }
}

// ---------------- 5. ctx_tmp partials (K-split, grid 32) -----------------------
__global__ __launch_bounds__(256) void ctx_tmp_kernel(
    const float* __restrict__ a_enc_part, const float* __restrict__ We,
    const float* __restrict__ be, float* __restrict__ ctmp)
{
    int kc = blockIdx.x >> 3, jc = blockIdx.x & 7;
    int tid = threadIdx.x;
    int j = jc * 256 + tid;
    int h = j >> 9;                       // uniform per block
    __shared__ float aes[16 * 128];
    for (int i = tid; i < 2048; i += 256) {
        int nn = i >> 7, kk = i & 127;
        float s = 0.f;
        for (int tc = 0; tc < 32; tc++)
            s += a_enc_part[(((long long)tc * NB + nn) * HH + h) * ENC + kc * 128 + kk];
        aes[i] = s;
    }
    __syncthreads();
    float acc[NB];
    #pragma unroll
    for (int n = 0; n < NB; n++) acc[n] = 0.f;
    const float4* w4 = (const float4*)(We + (long long)j * 512 + kc * 128);
    for (int e4 = 0; e4 < 32; e4++) {
        float4 w = w4[e4];
        #pragma unroll
        for (int n = 0; n < NB; n++) {
            const float* a = aes + n * 128 + e4 * 4;
            acc[n] += w.x * a[0] + w.y * a[1] + w.z * a[2] + w.w * a[3];
        }
    }
    float bias = (kc == 0) ? be[j] : 0.f;
    #pragma unroll
    for (int n = 0; n < NB; n++)
        ctmp[((long long)kc * NB + n) * HATT + j] = acc[n] + bias;
}

// ---------------- 6. ctx_out (grid 16 = 8 eo-chunks x 2 n-chunks) --------------
__global__ __launch_bounds__(256) void ctx_out_kernel(
    const float* __restrict__ ctmp, const float* __restrict__ Wc,
    const float* __restrict__ bc, float* __restrict__ out_ctx)
{
    int ec = blockIdx.x & 7, nc = blockIdx.x >> 3;
    int tid = threadIdx.x;
    __shared__ float ct[8 * 2048];        // 64 KB: ct[nn][j], nn = local n
    __shared__ float red[4][64][8];       // 8 KB
    for (int i = tid; i < 8 * 2048; i += 256) {
        int nn = i >> 11, j = i & 2047;
        int n = nc * 8 + nn;
        ct[i] = ctmp[((long long)0 * NB + n) * HATT + j]
              + ctmp[((long long)1 * NB + n) * HATT + j]
              + ctmp[((long long)2 * NB + n) * HATT + j]
              + ctmp[((long long)3 * NB + n) * HATT + j];
    }
    __syncthreads();
    int eo = tid & 63, kq = tid >> 6;     // 64 eo x 4 K-quarters
    int eg = ec * 64 + eo;
    float acc[8];
    #pragma unroll
    for (int nn = 0; nn < 8; nn++) acc[nn] = 0.f;
    const float4* w4 = (const float4*)(Wc + (long long)eg * HATT + kq * 512);
    for (int j4 = 0; j4 < 128; j4++) {
        float4 w = w4[j4];
        #pragma unroll
        for (int nn = 0; nn < 8; nn++) {
            const float* a = ct + nn * 2048 + kq * 512 + j4 * 4;
            acc[nn] += w.x * a[0] + w.y * a[1] + w.z * a[2] + w.w * a[3];
        }
    }
    #pragma unroll
    for (int nn = 0; nn < 8; nn++) red[kq][eo][nn] = acc[nn];
    __syncthreads();
    #pragma unroll
    for (int r = 0; r < 2; r++) {
        int idx = tid + r * 256;
        int eo2 = idx & 63, nn2 = idx >> 6;   // nn2 0..7
        float s = red[0][eo2][nn2] + red[1][eo2][nn2]
                + red[2][eo2][nn2] + red[3][eo2][nn2];
        out_ctx[((long long)(nc * 8 + nn2)) * 512 + ec * 64 + eo2] = s + bc[ec * 64 + eo2];
    }
}

// ---------------- launch ----------------
extern "C" void kernel_launch(void* const* d_in, const int* in_sizes, int n_in,
                              void* d_out, int out_size, void* d_ws, size_t ws_size,
                              hipStream_t stream)
{
    (void)in_sizes; (void)n_in; (void)out_size; (void)ws_size;
    const float* enc_pad  = (const float*)d_in[0];
    const int*   enc_len  = (const int*)  d_in[1];
    const float* dec_prev = (const float*)d_in[2];
    const float* ali_prev = (const float*)d_in[3];
    const float* We = (const float*)d_in[4];
    const float* be = (const float*)d_in[5];
    const float* Wk = (const float*)d_in[6];
    const float* Wd = (const float*)d_in[7];
    const float* WF = (const float*)d_in[8];
    const float* bF = (const float*)d_in[9];
    const float* Wa = (const float*)d_in[10];
    const float* Ww = (const float*)d_in[11];
    const float* Wc = (const float*)d_in[12];
    const float* bc = (const float*)d_in[13];

    char* ws = (char*)d_ws;
    u16*   Abf  = (u16*)  (ws);                 // 33,554,432 B
    u16*   Wkbf = (u16*)  (ws + 33554432);      //  2,097,152 B
    u16*   ftb  = (u16*)  (ws + 35651584);      //  4,194,304 B  [n*h][2048][16]
    u16*   wab  = (u16*)  (ws + 39845888);      //     65,536 B  [2048][16]
    float* decp = (float*)(ws + 39911424);      //    524,288 B  [4][16][2048]
    float* spart= (float*)(ws + 40435712);      //  2,048,000 B
    float* aep  = (float*)(ws + 40435712);      // alias spart region (dead after softmax)
    float* ctmp = (float*)(ws + 39911424);      // alias decp (dead after gemm)

    float* ali = (float*)d_out;                 // [16][4][2000]
    float* ctx = (float*)d_out + NB * HH * TT;  // [16][512]

    prep_kernel      <<<8996, 256, 0, stream>>>(enc_pad, Wk, ali_prev, WF, bF,
                                                dec_prev, Wd, Wa,
                                                Abf, Wkbf, ftb, wab, decp);
    score_gemm_kernel<<<4096, 256, 0, stream>>>(Abf, Wkbf, ftb, wab, decp, Ww,
                                                enc_len, spart);
    softmax_kernel   <<<64,   256, 0, stream>>>(spart, enc_len, ali);
    a_enc_kernel     <<<512,  256, 0, stream>>>(ali, Abf, enc_len, aep);
    ctx_tmp_kernel   <<<32,   256, 0, stream>>>(aep, We, be, ctmp);
    ctx_out_kernel   <<<16,   256, 0, stream>>>(ctmp, Wc, bc, ctx);
}

// Round 8
// 182.597 us; speedup vs baseline: 2.7717x; 1.0503x over previous
//
#include <hip/hip_runtime.h>

// ---------------- problem dims ----------------
#define NB   16
#define TT   2000
#define TP   2048      // padded T for GEMM tiling
#define SPT  2048      // spart row stride (padded for float4 softmax loads)
#define ENC  512
#define ATTD 512
#define HH   4
#define CC   10
#define KK   64        // conv half-window
#define KW   129       // 2K+1
#define HATT 2048

typedef unsigned short u16;
typedef __attribute__((ext_vector_type(8))) short bf16x8;
typedef __attribute__((ext_vector_type(4))) float f32x4;

#define AS1 __attribute__((address_space(1)))
#define AS3 __attribute__((address_space(3)))

// round-to-nearest-even f32 -> bf16, packed pair
__device__ inline unsigned bfpack2(float lo, float hi) {
    unsigned a = __builtin_bit_cast(unsigned, lo);
    unsigned b = __builtin_bit_cast(unsigned, hi);
    a = (a + 0x7fffu + ((a >> 16) & 1u)) >> 16;
    b = (b + 0x7fffu + ((b >> 16) & 1u)) >> 16;
    return a | (b << 16);
}

// ---------------- 1. fused prep: convert + conv_f(->bf16 f^T) + dec + Wa pack --
__global__ __launch_bounds__(256) void prep_kernel(
    const float* __restrict__ enc, const float* __restrict__ Wk,
    const float* __restrict__ ali_prev, const float* __restrict__ WF,
    const float* __restrict__ bF, const float* __restrict__ dec_prev,
    const float* __restrict__ Wd, const float* __restrict__ Wa,
    const int* __restrict__ enc_len,
    u16* __restrict__ Abf, u16* __restrict__ Wkbf,
    u16* __restrict__ ftb, u16* __restrict__ wab,
    float* __restrict__ decp)
{
    __shared__ union {
        struct { float aliW[632]; float wfT[KW * CC]; float bfs[CC]; } cv;
        float dsl[16 * 128];
    } sm;
    const int bid = blockIdx.x, tid = threadIdx.x;

    if (bid < 8704) {
        // ---- bf16 convert; rows t >= enc_len[n] skipped (masked downstream) ----
        long long gid = ((long long)bid * 256 + tid) * 8;
        const long long ATOT = (long long)NB * TP * ENC;   // 1<<24
        if (gid < ATOT) {
            int n = (int)(gid >> 20);
            int rem = (int)(gid & ((1 << 20) - 1));
            int r = rem >> 9, e = rem & 511;
            if (r < enc_len[n]) {
                const float* s = enc + ((long long)n * TT + r) * ENC + e;
                float4 v0 = *(const float4*)s;
                float4 v1 = *(const float4*)(s + 4);
                uint4 out;
                out.x = bfpack2(v0.x, v0.y); out.y = bfpack2(v0.z, v0.w);
                out.z = bfpack2(v1.x, v1.y); out.w = bfpack2(v1.z, v1.w);
                *(uint4*)(Abf + gid) = out;
            }
        } else {
            long long j = gid - ATOT;                       // < 2048*512
            const float* s = Wk + j;
            float4 v0 = *(const float4*)s;
            float4 v1 = *(const float4*)(s + 4);
            uint4 out;
            out.x = bfpack2(v0.x, v0.y); out.y = bfpack2(v0.z, v0.w);
            out.z = bfpack2(v1.x, v1.y); out.w = bfpack2(v1.z, v1.w);
            *(uint4*)(Wkbf + j) = out;
        }
    } else if (bid < 8960) {
        // ---- grouped conv1d, register accumulators; writes ftb[t][16] bf16 ----
        int b2 = bid - 8704;
        int tc = b2 & 3, h = (b2 >> 2) & 3, n = b2 >> 4;
        int t0 = tc * 500;
        float* aliW = sm.cv.aliW;
        float* wfT  = sm.cv.wfT;       // [k][c] layout
        float* bfs  = sm.cv.bfs;
        const float* arow = ali_prev + ((long long)n * HH + h) * TT;
        for (int i = tid; i < 632; i += 256) {
            int tt = t0 - KK + i;
            aliW[i] = (tt >= 0 && tt < TT) ? arow[tt] : 0.f;
        }
        for (int i = tid; i < KW * CC; i += 256) {
            int k = i / CC, c = i - k * CC;
            wfT[i] = WF[(h * CC + c) * KW + k];
        }
        if (tid < CC) bfs[tid] = bF[h * CC + tid];
        __syncthreads();
        if (tid < 250) {
            float acc0[CC], acc1[CC];
            #pragma unroll
            for (int c = 0; c < CC; c++) { acc0[c] = 0.f; acc1[c] = 0.f; }
            const int base = 2 * tid;
            float2 w0 = *(const float2*)&aliW[base];
            for (int k = 0; k < 128; k += 2) {
                float2 w2 = *(const float2*)&aliW[base + k + 2];
                #pragma unroll
                for (int cj = 0; cj < 5; cj++) {
                    float2 fk  = *(const float2*)&wfT[k * CC + cj * 2];
                    float2 fk1 = *(const float2*)&wfT[(k + 1) * CC + cj * 2];
                    acc0[2*cj]   += w0.x * fk.x + w0.y * fk1.x;
                    acc0[2*cj+1] += w0.x * fk.y + w0.y * fk1.y;
                    acc1[2*cj]   += w0.y * fk.x + w2.x * fk1.x;
                    acc1[2*cj+1] += w0.y * fk.y + w2.x * fk1.y;
                }
                w0 = w2;
            }
            #pragma unroll
            for (int cj = 0; cj < 5; cj++) {
                float2 fk = *(const float2*)&wfT[128 * CC + cj * 2];
                acc0[2*cj]   += w0.x * fk.x;  acc0[2*cj+1] += w0.x * fk.y;
                acc1[2*cj]   += w0.y * fk.x;  acc1[2*cj+1] += w0.y * fk.y;
            }
            #pragma unroll
            for (int c = 0; c < CC; c++) { acc0[c] += bfs[c]; acc1[c] += bfs[c]; }
            int t = t0 + base;
            u16* frow = ftb + (((long long)(n * HH + h)) * TP + t) * 16;
            uint4 ra, rb;
            ra.x = bfpack2(acc0[0], acc0[1]); ra.y = bfpack2(acc0[2], acc0[3]);
            ra.z = bfpack2(acc0[4], acc0[5]); ra.w = bfpack2(acc0[6], acc0[7]);
            rb.x = bfpack2(acc0[8], acc0[9]); rb.y = 0u; rb.z = 0u; rb.w = 0u;
            *(uint4*)(frow)     = ra; *(uint4*)(frow + 8)  = rb;
            ra.x = bfpack2(acc1[0], acc1[1]); ra.y = bfpack2(acc1[2], acc1[3]);
            ra.z = bfpack2(acc1[4], acc1[5]); ra.w = bfpack2(acc1[6], acc1[7]);
            rb.x = bfpack2(acc1[8], acc1[9]);
            *(uint4*)(frow + 16) = ra; *(uint4*)(frow + 24) = rb;
        } else if (tc == 3) {
            // zero-pad ftb rows t in [2000, 2048)
            uint4 z = {0u, 0u, 0u, 0u};
            int r0 = 2000 + (tid - 250) * 8;
            u16* frow = ftb + (((long long)(n * HH + h)) * TP + r0) * 16;
            for (int r = 0; r < 8; r++) {
                *(uint4*)(frow + r * 16)     = z;
                *(uint4*)(frow + r * 16 + 8) = z;
            }
        }
    } else if (bid < 8992) {
        // ---- dec_part K-split partials: decp[kc][n][d] ----
        int b2 = bid - 8960;                 // 0..31
        int kc = b2 >> 3, jc = b2 & 7;
        for (int i = tid; i < 2048; i += 256) {
            int nn = i >> 7, kk = i & 127;
            sm.dsl[i] = dec_prev[nn * 512 + kc * 128 + kk];
        }
        __syncthreads();
        int d = jc * 256 + tid;
        float acc[NB];
        #pragma unroll
        for (int n = 0; n < NB; n++) acc[n] = 0.f;
        const float4* w4 = (const float4*)(Wd + (long long)d * 512 + kc * 128);
        for (int e4 = 0; e4 < 32; e4++) {
            float4 w = w4[e4];
            #pragma unroll
            for (int n = 0; n < NB; n++) {
                const float* a = sm.dsl + n * 128 + e4 * 4;
                acc[n] += w.x * a[0] + w.y * a[1] + w.z * a[2] + w.w * a[3];
            }
        }
        #pragma unroll
        for (int n = 0; n < NB; n++) decp[((long long)kc * NB + n) * HATT + d] = acc[n];
    } else {
        // ---- wab[j][16] = Wa[j>>9][j&511][0..9] bf16 (B-ext rows) ----
        int b2 = bid - 8992;                 // 0..3
        int j0 = b2 * 512 + tid * 2;
        #pragma unroll
        for (int q = 0; q < 2; q++) {
            int j = j0 + q;
            int hh = j >> 9, dd = j & 511;
            const float* wr = Wa + ((long long)(hh * ATTD + dd)) * CC;
            uint4 ra, rb;
            ra.x = bfpack2(wr[0], wr[1]); ra.y = bfpack2(wr[2], wr[3]);
            ra.z = bfpack2(wr[4], wr[5]); ra.w = bfpack2(wr[6], wr[7]);
            rb.x = bfpack2(wr[8], wr[9]); rb.y = 0u; rb.z = 0u; rb.w = 0u;
            u16* out = wab + (long long)j * 16;
            *(uint4*)(out)     = ra;
            *(uint4*)(out + 8) = rb;
        }
    }
}

// ---------------- 2. fused GEMM with att folded into K (K = 512 + 32ext) -------
__global__ __launch_bounds__(256, 4) void score_gemm_kernel(
    const u16* __restrict__ Abf, const u16* __restrict__ Bbf,
    const u16* __restrict__ ftb, const u16* __restrict__ wab,
    const float* __restrict__ decp, const float* __restrict__ Ww,
    const int* __restrict__ enc_len, float* __restrict__ score_part)
{
    __shared__ __attribute__((aligned(16))) char smem[40960];
    // [0,16384) lA | [16384,32768) lB | [32768,36864) extA | [36864,40960) extB
    float* sred = (float*)smem;      // reused after final barrier

    const int bid = blockIdx.x;
    const int swz = (bid & 7) * 512 + (bid >> 3);   // T1: contiguous chunk per XCD
    const int nt = swz & 15, mt = (swz >> 4) & 15, n = swz >> 8;

    if (mt * 128 >= enc_len[n]) return;   // fully-masked M-tile

    const int tid = threadIdx.x, wave = tid >> 6, lane = tid & 63;
    const int l16 = lane & 15, lk = lane >> 4;
    const int h = nt >> 2;

    const u16* Aptr = Abf + ((long long)n * TP + mt * 128) * ENC;
    const u16* Bptr = Bbf + (long long)nt * 128 * ENC;

    f32x4 acc[4][4];
    #pragma unroll
    for (int mi = 0; mi < 4; mi++)
        #pragma unroll
        for (int nj = 0; nj < 4; nj++) {
            f32x4 z = {0.f, 0.f, 0.f, 0.f};
            acc[mi][nj] = z;
        }

    const int wrow = (wave >> 1) * 64, wcol = (wave & 1) * 64;
    const int t0 = mt * 128, dd0 = (nt & 3) * 128;

    {
        const char* eAsrc = (const char*)(ftb + (((long long)(n * HH + h)) * TP + t0) * 16);
        const char* eBsrc = (const char*)(wab + (long long)nt * 128 * 16);
        __builtin_amdgcn_global_load_lds(
            (const AS1 void*)(eAsrc + tid * 16),
            (AS3 void*)(smem + 32768 + wave * 1024), 16, 0, 0);
        __builtin_amdgcn_global_load_lds(
            (const AS1 void*)(eBsrc + tid * 16),
            (AS3 void*)(smem + 36864 + wave * 1024), 16, 0, 0);
    }

    for (int kt = 0; kt < 8; kt++) {
        const int k0 = kt * 64;
        #pragma unroll
        for (int i = 0; i < 4; i++) {
            int b = i * 4096 + tid * 16;
            int r = b >> 7, kb = b & 127;
            int kbs = kb ^ ((r & 7) << 4);
            __builtin_amdgcn_global_load_lds(
                (const AS1 void*)(Aptr + r * ENC + k0 + (kbs >> 1)),
                (AS3 void*)(smem + i * 4096 + wave * 1024), 16, 0, 0);
            __builtin_amdgcn_global_load_lds(
                (const AS1 void*)(Bptr + r * ENC + k0 + (kbs >> 1)),
                (AS3 void*)(smem + 16384 + i * 4096 + wave * 1024), 16, 0, 0);
        }
        __syncthreads();
        #pragma unroll
        for (int ks = 0; ks < 64; ks += 32) {
            bf16x8 af[4], bf[4];
            #pragma unroll
            for (int mi = 0; mi < 4; mi++) {
                int row = wrow + mi * 16 + l16;
                int cb = (ks * 2 + lk * 16) ^ ((row & 7) << 4);
                af[mi] = *(const bf16x8*)(smem + row * 128 + cb);
            }
            #pragma unroll
            for (int nj = 0; nj < 4; nj++) {
                int row = wcol + nj * 16 + l16;
                int cb = (ks * 2 + lk * 16) ^ ((row & 7) << 4);
                bf[nj] = *(const bf16x8*)(smem + 16384 + row * 128 + cb);
            }
            #pragma unroll
            for (int mi = 0; mi < 4; mi++)
                #pragma unroll
                for (int nj = 0; nj < 4; nj++)
                    acc[mi][nj] = __builtin_amdgcn_mfma_f32_16x16x32_bf16(
                        af[mi], bf[nj], acc[mi][nj], 0, 0, 0);
        }
        __syncthreads();
    }

    // ---- K-extension step: att fold (c 0..9 valid, upper K zero) ----
    {
        const u16* eA = (const u16*)(smem + 32768);
        const u16* eB = (const u16*)(smem + 36864);
        bf16x8 zer = {0, 0, 0, 0, 0, 0, 0, 0};
        bf16x8 af[4], bf[4];
        #pragma unroll
        for (int mi = 0; mi < 4; mi++) {
            af[mi] = zer;
            if (lk < 2) af[mi] = *(const bf16x8*)(eA + (wrow + mi * 16 + l16) * 16 + lk * 8);
        }
        #pragma unroll
        for (int nj = 0; nj < 4; nj++) {
            bf[nj] = zer;
            if (lk < 2) bf[nj] = *(const bf16x8*)(eB + (wcol + nj * 16 + l16) * 16 + lk * 8);
        }
        #pragma unroll
        for (int mi = 0; mi < 4; mi++)
            #pragma unroll
            for (int nj = 0; nj < 4; nj++)
                acc[mi][nj] = __builtin_amdgcn_mfma_f32_16x16x32_bf16(
                    af[mi], bf[nj], acc[mi][nj], 0, 0, 0);
    }

    // ---- epilogue: score'= sum_d -2*ww*rcp(exp(2v)+1)  (shift cancels in softmax)
    float wm2[4], dec4[4];
    #pragma unroll
    for (int nj = 0; nj < 4; nj++) {
        int cl = wcol + nj * 16 + l16;
        wm2[nj] = -2.f * Ww[h * ATTD + dd0 + cl];
        int j = nt * 128 + cl;
        dec4[nj] = decp[((long long)0 * NB + n) * HATT + j]
                 + decp[((long long)1 * NB + n) * HATT + j]
                 + decp[((long long)2 * NB + n) * HATT + j]
                 + decp[((long long)3 * NB + n) * HATT + j];
    }

    #pragma unroll
    for (int mi = 0; mi < 4; mi++) {
        #pragma unroll
        for (int j = 0; j < 4; j++) {
            int rl = wrow + mi * 16 + lk * 4 + j;
            float s = 0.f;
            #pragma unroll
            for (int nj = 0; nj < 4; nj++) {
                float v = acc[mi][nj][j] + dec4[nj];
                float e = __expf(v + v);
                s = fmaf(wm2[nj], __builtin_amdgcn_rcpf(e + 1.f), s);
            }
            s += __shfl_xor(s, 1); s += __shfl_xor(s, 2);
            s += __shfl_xor(s, 4); s += __shfl_xor(s, 8);
            if (l16 == 0) sred[(wave & 1) * 128 + rl] = s;
        }
    }
    __syncthreads();
    if (tid < 128) {
        int t = t0 + tid;
        if (t < TT)
            score_part[((long long)((nt & 3) * NB + n) * HH + h) * SPT + t] =
                sred[tid] + sred[128 + tid];
    }
}

// ---------------- 3. masked softmax (float4 path; thread owns 8 consecutive t) -
__global__ __launch_bounds__(256) void softmax_kernel(
    const float* __restrict__ score_part, const int* __restrict__ enc_len,
    float* __restrict__ ali)
{
    int n = blockIdx.x >> 2, h = blockIdx.x & 3;
    int len = enc_len[n];
    int tid = threadIdx.x;
    int t0 = tid * 8;
    float s[8];
    #pragma unroll
    for (int i = 0; i < 8; i++) s[i] = 0.f;
    #pragma unroll
    for (int q = 0; q < 4; q++) {
        const float* rb = score_part + (((long long)(q * NB + n)) * HH + h) * SPT + t0;
        float4 a = *(const float4*)rb;
        float4 b = *(const float4*)(rb + 4);
        s[0] += a.x; s[1] += a.y; s[2] += a.z; s[3] += a.w;
        s[4] += b.x; s[5] += b.y; s[6] += b.z; s[7] += b.w;
    }
    float lmax = -3.4e38f;
    #pragma unroll
    for (int i = 0; i < 8; i++) {
        if (t0 + i < len) lmax = fmaxf(lmax, s[i]);
    }
    __shared__ float red[256];
    red[tid] = lmax; __syncthreads();
    for (int off = 128; off; off >>= 1) {
        if (tid < off) red[tid] = fmaxf(red[tid], red[tid + off]);
        __syncthreads();
    }
    float bmax = red[0];
    __syncthreads();
    float lsum = 0.f;
    #pragma unroll
    for (int i = 0; i < 8; i++) {
        if (t0 + i < len) { s[i] = expf(s[i] - bmax); lsum += s[i]; }
        else s[i] = 0.f;
    }
    red[tid] = lsum; __syncthreads();
    for (int off = 128; off; off >>= 1) {
        if (tid < off) red[tid] += red[tid + off];
        __syncthreads();
    }
    float inv = 1.f / red[0];
    float* arow = ali + ((long long)n * HH + h) * TT;
    if (t0 + 8 <= TT) {
        float4 o0 = {s[0] * inv, s[1] * inv, s[2] * inv, s[3] * inv};
        float4 o1 = {s[4] * inv, s[5] * inv, s[6] * inv, s[7] * inv};
        *(float4*)(arow + t0) = o0;
        *(float4*)(arow + t0 + 4) = o1;
    } else {
        for (int i = 0; i < 8; i++)
            if (t0 + i < TT) arow[t0 + i] = s[i] * inv;
    }
}

// ---------------- 4. a_enc partials: uint2 bf16 loads, 2 rows in flight --------
__global__ __launch_bounds__(256) void a_enc_kernel(
    const float* __restrict__ ali, const u16* __restrict__ Abf,
    const int* __restrict__ enc_len, float* __restrict__ aep)
{
    int tc = blockIdx.x & 31, n = blockIdx.x >> 5;
    int tid = threadIdx.x;
    int len = enc_len[n];
    int tbeg = tc * 63;
    int cnt = len - tbeg; if (cnt > 63) cnt = 63; if (cnt < 0) cnt = 0;
    __shared__ float aliS[HH][64];
    __shared__ float red[2][4][129];   // [tq][k][lane] transposed: conflict-free
    {
        int hh = tid >> 6, tt = tid & 63;
        aliS[hh][tt] = (tt < cnt) ? ali[((long long)n * HH + hh) * TT + tbeg + tt] : 0.f;
    }
    __syncthreads();
    const int l = tid & 127, tq = tid >> 7;   // dims 4l..4l+3; rows tl = 2*ii+tq
    float acc[HH][4];
    #pragma unroll
    for (int hh = 0; hh < HH; hh++)
        #pragma unroll
        for (int k = 0; k < 4; k++) acc[hh][k] = 0.f;
    for (int ii = 0; ii < 32; ii++) {
        int tl = ii * 2 + tq;
        if (tl < cnt) {   // explicit guard: never touch unconverted rows
            uint2 u = *(const uint2*)(Abf + ((long long)n * TP + tbeg + tl) * ENC + l * 4);
            float e0 = __builtin_bit_cast(float, u.x << 16);
            float e1 = __builtin_bit_cast(float, u.x & 0xffff0000u);
            float e2 = __builtin_bit_cast(float, u.y << 16);
            float e3 = __builtin_bit_cast(float, u.y & 0xffff0000u);
            #pragma unroll
            for (int hh = 0; hh < HH; hh++) {
                float w = aliS[hh][tl];
                acc[hh][0] += w * e0; acc[hh][1] += w * e1;
                acc[hh][2] += w * e2; acc[hh][3] += w * e3;
            }
        }
    }
    #pragma unroll
    for (int hh = 0; hh < HH; hh++) {
        __syncthreads();
        #pragma unroll
        for (int k = 0; k < 4; k++) red[tq][k][l] = acc[hh][k];
        __syncthreads();
        int d2 = tid * 2;
        float v0 = red[0][d2 & 3][d2 >> 2] + red[1][d2 & 3][d2 >> 2];
        int d3 = d2 + 1;
        float v1 = red[0][d3 & 3][d3 >> 2] + red[1][d3 & 3][d3 >> 2];
        float2 o = {v0, v1};
        *(float2*)(aep + (((long long)tc * NB + n) * HH + hh) * ENC + d2) = o;
    }
}

// ---------------- 5. ctx_tmp partials (K-split 8, grid 64) ---------------------
__global__ __launch_bounds__(256) void ctx_tmp_kernel(
    const float* __restrict__ aep, const float* __restrict__ We,
    const float* __restrict__ be, float* __restrict__ ctmp)
{
    int kc = blockIdx.x >> 3, jc = blockIdx.x & 7;   // kc 0..7 (64-K), jc 0..7
    int tid = threadIdx.x;
    int j = jc * 256 + tid;
    int h = j >> 9;                       // uniform per block
    __shared__ float aes[16 * 64];
    for (int i = tid; i < 1024; i += 256) {
        int nn = i >> 6, kk = i & 63;
        float s = 0.f;
        for (int tc = 0; tc < 32; tc++)
            s += aep[(((long long)tc * NB + nn) * HH + h) * ENC + kc * 64 + kk];
        aes[i] = s;
    }
    __syncthreads();
    float acc[NB];
    #pragma unroll
    for (int n = 0; n < NB; n++) acc[n] = 0.f;
    const float4* w4 = (const float4*)(We + (long long)j * 512 + kc * 64);
    for (int e4 = 0; e4 < 16; e4++) {
        float4 w = w4[e4];
        #pragma unroll
        for (int n = 0; n < NB; n++) {
            const float* a = aes + n * 64 + e4 * 4;
            acc[n] += w.x * a[0] + w.y * a[1] + w.z * a[2] + w.w * a[3];
        }
    }
    float bias = (kc == 0) ? be[j] : 0.f;
    #pragma unroll
    for (int n = 0; n < NB; n++)
        ctmp[((long long)kc * NB + n) * HATT + j] = acc[n] + bias;
}

// ---------------- 6. ctx_out (grid 32 = 16 ec x 2 nc) --------------------------
__global__ __launch_bounds__(256) void ctx_out_kernel(
    const float* __restrict__ ctmp, const float* __restrict__ Wc,
    const float* __restrict__ bc, float* __restrict__ out_ctx)
{
    int ec = blockIdx.x & 15, nc = blockIdx.x >> 4;
    int tid = threadIdx.x;
    __shared__ float ct[8 * 2048];        // 64 KB: ct[nn][j]
    __shared__ float red[8][8][33];       // [kq][nn][eo+pad]: conflict-free
    for (int i = tid; i < 8 * 2048; i += 256) {
        int nn = i >> 11, j = i & 2047;
        int n = nc * 8 + nn;
        float s = 0.f;
        #pragma unroll
        for (int kc = 0; kc < 8; kc++)
            s += ctmp[((long long)kc * NB + n) * HATT + j];
        ct[i] = s;
    }
    __syncthreads();
    int eo = tid & 31, kq = tid >> 5;     // 32 eo x 8 K-slices (256 j each)
    int eg = ec * 32 + eo;
    float acc[8];
    #pragma unroll
    for (int nn = 0; nn < 8; nn++) acc[nn] = 0.f;
    const float4* w4 = (const float4*)(Wc + (long long)eg * HATT + kq * 256);
    for (int j4 = 0; j4 < 64; j4++) {
        float4 w = w4[j4];
        #pragma unroll
        for (int nn = 0; nn < 8; nn++) {
            const float* a = ct + nn * 2048 + kq * 256 + j4 * 4;
            acc[nn] += w.x * a[0] + w.y * a[1] + w.z * a[2] + w.w * a[3];
        }
    }
    #pragma unroll
    for (int nn = 0; nn < 8; nn++) red[kq][nn][eo] = acc[nn];
    __syncthreads();
    {
        int eo2 = tid & 31, nn2 = tid >> 5;   // 256 threads = 32 eo x 8 nn
        float s = 0.f;
        #pragma unroll
        for (int kq2 = 0; kq2 < 8; kq2++) s += red[kq2][nn2][eo2];
        out_ctx[((long long)(nc * 8 + nn2)) * 512 + ec * 32 + eo2] = s + bc[ec * 32 + eo2];
    }
}

// ---------------- launch ----------------
extern "C" void kernel_launch(void* const* d_in, const int* in_sizes, int n_in,
                              void* d_out, int out_size, void* d_ws, size_t ws_size,
                              hipStream_t stream)
{
    (void)in_sizes; (void)n_in; (void)out_size; (void)ws_size;
    const float* enc_pad  = (const float*)d_in[0];
    const int*   enc_len  = (const int*)  d_in[1];
    const float* dec_prev = (const float*)d_in[2];
    const float* ali_prev = (const float*)d_in[3];
    const float* We = (const float*)d_in[4];
    const float* be = (const float*)d_in[5];
    const float* Wk = (const float*)d_in[6];
    const float* Wd = (const float*)d_in[7];
    const float* WF = (const float*)d_in[8];
    const float* bF = (const float*)d_in[9];
    const float* Wa = (const float*)d_in[10];
    const float* Ww = (const float*)d_in[11];
    const float* Wc = (const float*)d_in[12];
    const float* bc = (const float*)d_in[13];

    char* ws = (char*)d_ws;
    u16*   Abf  = (u16*)  (ws);                 // 33,554,432 B
    u16*   Wkbf = (u16*)  (ws + 33554432);      //  2,097,152 B
    u16*   ftb  = (u16*)  (ws + 35651584);      //  4,194,304 B  [n*h][2048][16]
    u16*   wab  = (u16*)  (ws + 39845888);      //     65,536 B  [2048][16]
    float* decp = (float*)(ws + 39911424);      //    524,288 B  [4][16][2048]
    float* spart= (float*)(ws + 40435712);      //  2,097,152 B  [4][16][4][2048]
    float* aep  = (float*)(ws + 40435712);      // alias spart (dead after softmax), 4 MB
    float* ctmp = (float*)(ws + 35651584);      // alias ftb (dead after gemm), 1 MB
    // high-water 44,630,016 B (same proven envelope as round 5-7)

    float* ali = (float*)d_out;                 // [16][4][2000]
    float* ctx = (float*)d_out + NB * HH * TT;  // [16][512]

    prep_kernel      <<<8996, 256, 0, stream>>>(enc_pad, Wk, ali_prev, WF, bF,
                                                dec_prev, Wd, Wa, enc_len,
                                                Abf, Wkbf, ftb, wab, decp);
    score_gemm_kernel<<<4096, 256, 0, stream>>>(Abf, Wkbf, ftb, wab, decp, Ww,
                                                enc_len, spart);
    softmax_kernel   <<<64,   256, 0, stream>>>(spart, enc_len, ali);
    a_enc_kernel     <<<512,  256, 0, stream>>>(ali, Abf, enc_len, aep);
    ctx_tmp_kernel   <<<64,   256, 0, stream>>>(aep, We, be, ctmp);
    ctx_out_kernel   <<<32,   256, 0, stream>>>(ctmp, Wc, bc, ctx);
}

// Round 9
// 174.428 us; speedup vs baseline: 2.9015x; 1.0468x over previous
//
#include <hip/hip_runtime.h>

// ---------------- problem dims ----------------
#define NB   16
#define TT   2000
#define TP   2048      // padded T for GEMM tiling
#define SPT  2048      // spart row stride (padded for float4 softmax loads)
#define ENC  512
#define ATTD 512
#define HH   4
#define CC   10
#define KK   64        // conv half-window
#define KW   129       // 2K+1
#define HATT 2048

typedef unsigned short u16;
typedef __attribute__((ext_vector_type(8))) short bf16x8;
typedef __attribute__((ext_vector_type(4))) float f32x4;

#define AS1 __attribute__((address_space(1)))
#define AS3 __attribute__((address_space(3)))

// round-to-nearest-even f32 -> bf16, packed pair
__device__ inline unsigned bfpack2(float lo, float hi) {
    unsigned a = __builtin_bit_cast(unsigned, lo);
    unsigned b = __builtin_bit_cast(unsigned, hi);
    a = (a + 0x7fffu + ((a >> 16) & 1u)) >> 16;
    b = (b + 0x7fffu + ((b >> 16) & 1u)) >> 16;
    return a | (b << 16);
}

// ---------------- 1. fused prep: convert + conv_f(->bf16 f^T) + dec + Wa pack --
__global__ __launch_bounds__(256) void prep_kernel(
    const float* __restrict__ enc, const float* __restrict__ Wk,
    const float* __restrict__ ali_prev, const float* __restrict__ WF,
    const float* __restrict__ bF, const float* __restrict__ dec_prev,
    const float* __restrict__ Wd, const float* __restrict__ Wa,
    const int* __restrict__ enc_len,
    u16* __restrict__ Abf, u16* __restrict__ Wkbf,
    u16* __restrict__ ftb, u16* __restrict__ wab,
    float* __restrict__ decp)
{
    __shared__ union {
        struct { float aliW[632]; float wfT[KW * CC]; float bfs[CC]; } cv;
        float dsl[16 * 128];
    } sm;
    const int bid = blockIdx.x, tid = threadIdx.x;

    if (bid < 8704) {
        // ---- bf16 convert; rows t >= enc_len[n] skipped (masked downstream) ----
        long long gid = ((long long)bid * 256 + tid) * 8;
        const long long ATOT = (long long)NB * TP * ENC;   // 1<<24
        if (gid < ATOT) {
            int n = (int)(gid >> 20);
            int rem = (int)(gid & ((1 << 20) - 1));
            int r = rem >> 9, e = rem & 511;
            if (r < enc_len[n]) {
                const float* s = enc + ((long long)n * TT + r) * ENC + e;
                float4 v0 = *(const float4*)s;
                float4 v1 = *(const float4*)(s + 4);
                uint4 out;
                out.x = bfpack2(v0.x, v0.y); out.y = bfpack2(v0.z, v0.w);
                out.z = bfpack2(v1.x, v1.y); out.w = bfpack2(v1.z, v1.w);
                *(uint4*)(Abf + gid) = out;
            }
        } else {
            long long j = gid - ATOT;                       // < 2048*512
            const float* s = Wk + j;
            float4 v0 = *(const float4*)s;
            float4 v1 = *(const float4*)(s + 4);
            uint4 out;
            out.x = bfpack2(v0.x, v0.y); out.y = bfpack2(v0.z, v0.w);
            out.z = bfpack2(v1.x, v1.y); out.w = bfpack2(v1.z, v1.w);
            *(uint4*)(Wkbf + j) = out;
        }
    } else if (bid < 8960) {
        // ---- grouped conv1d, register accumulators; writes ftb[t][16] bf16 ----
        int b2 = bid - 8704;
        int tc = b2 & 3, h = (b2 >> 2) & 3, n = b2 >> 4;
        int t0 = tc * 500;
        float* aliW = sm.cv.aliW;
        float* wfT  = sm.cv.wfT;       // [k][c] layout
        float* bfs  = sm.cv.bfs;
        const float* arow = ali_prev + ((long long)n * HH + h) * TT;
        for (int i = tid; i < 632; i += 256) {
            int tt = t0 - KK + i;
            aliW[i] = (tt >= 0 && tt < TT) ? arow[tt] : 0.f;
        }
        for (int i = tid; i < KW * CC; i += 256) {
            int k = i / CC, c = i - k * CC;
            wfT[i] = WF[(h * CC + c) * KW + k];
        }
        if (tid < CC) bfs[tid] = bF[h * CC + tid];
        __syncthreads();
        if (tid < 250) {
            float acc0[CC], acc1[CC];
            #pragma unroll
            for (int c = 0; c < CC; c++) { acc0[c] = 0.f; acc1[c] = 0.f; }
            const int base = 2 * tid;
            float2 w0 = *(const float2*)&aliW[base];
            for (int k = 0; k < 128; k += 2) {
                float2 w2 = *(const float2*)&aliW[base + k + 2];
                #pragma unroll
                for (int cj = 0; cj < 5; cj++) {
                    float2 fk  = *(const float2*)&wfT[k * CC + cj * 2];
                    float2 fk1 = *(const float2*)&wfT[(k + 1) * CC + cj * 2];
                    acc0[2*cj]   += w0.x * fk.x + w0.y * fk1.x;
                    acc0[2*cj+1] += w0.x * fk.y + w0.y * fk1.y;
                    acc1[2*cj]   += w0.y * fk.x + w2.x * fk1.x;
                    acc1[2*cj+1] += w0.y * fk.y + w2.x * fk1.y;
                }
                w0 = w2;
            }
            #pragma unroll
            for (int cj = 0; cj < 5; cj++) {
                float2 fk = *(const float2*)&wfT[128 * CC + cj * 2];
                acc0[2*cj]   += w0.x * fk.x;  acc0[2*cj+1] += w0.x * fk.y;
                acc1[2*cj]   += w0.y * fk.x;  acc1[2*cj+1] += w0.y * fk.y;
            }
            #pragma unroll
            for (int c = 0; c < CC; c++) { acc0[c] += bfs[c]; acc1[c] += bfs[c]; }
            int t = t0 + base;
            u16* frow = ftb + (((long long)(n * HH + h)) * TP + t) * 16;
            uint4 ra, rb;
            ra.x = bfpack2(acc0[0], acc0[1]); ra.y = bfpack2(acc0[2], acc0[3]);
            ra.z = bfpack2(acc0[4], acc0[5]); ra.w = bfpack2(acc0[6], acc0[7]);
            rb.x = bfpack2(acc0[8], acc0[9]); rb.y = 0u; rb.z = 0u; rb.w = 0u;
            *(uint4*)(frow)     = ra; *(uint4*)(frow + 8)  = rb;
            ra.x = bfpack2(acc1[0], acc1[1]); ra.y = bfpack2(acc1[2], acc1[3]);
            ra.z = bfpack2(acc1[4], acc1[5]); ra.w = bfpack2(acc1[6], acc1[7]);
            rb.x = bfpack2(acc1[8], acc1[9]);
            *(uint4*)(frow + 16) = ra; *(uint4*)(frow + 24) = rb;
        } else if (tc == 3) {
            // zero-pad ftb rows t in [2000, 2048)
            uint4 z = {0u, 0u, 0u, 0u};
            int r0 = 2000 + (tid - 250) * 8;
            u16* frow = ftb + (((long long)(n * HH + h)) * TP + r0) * 16;
            for (int r = 0; r < 8; r++) {
                *(uint4*)(frow + r * 16)     = z;
                *(uint4*)(frow + r * 16 + 8) = z;
            }
        }
    } else if (bid < 8992) {
        // ---- dec_part K-split partials: decp[kc][n][d] ----
        int b2 = bid - 8960;                 // 0..31
        int kc = b2 >> 3, jc = b2 & 7;
        for (int i = tid; i < 2048; i += 256) {
            int nn = i >> 7, kk = i & 127;
            sm.dsl[i] = dec_prev[nn * 512 + kc * 128 + kk];
        }
        __syncthreads();
        int d = jc * 256 + tid;
        float acc[NB];
        #pragma unroll
        for (int n = 0; n < NB; n++) acc[n] = 0.f;
        const float4* w4 = (const float4*)(Wd + (long long)d * 512 + kc * 128);
        for (int e4 = 0; e4 < 32; e4++) {
            float4 w = w4[e4];
            #pragma unroll
            for (int n = 0; n < NB; n++) {
                const float* a = sm.dsl + n * 128 + e4 * 4;
                acc[n] += w.x * a[0] + w.y * a[1] + w.z * a[2] + w.w * a[3];
            }
        }
        #pragma unroll
        for (int n = 0; n < NB; n++) decp[((long long)kc * NB + n) * HATT + d] = acc[n];
    } else {
        // ---- wab[j][16] = Wa[j>>9][j&511][0..9] bf16 (B-ext rows) ----
        int b2 = bid - 8992;                 // 0..3
        int j0 = b2 * 512 + tid * 2;
        #pragma unroll
        for (int q = 0; q < 2; q++) {
            int j = j0 + q;
            int hh = j >> 9, dd = j & 511;
            const float* wr = Wa + ((long long)(hh * ATTD + dd)) * CC;
            uint4 ra, rb;
            ra.x = bfpack2(wr[0], wr[1]); ra.y = bfpack2(wr[2], wr[3]);
            ra.z = bfpack2(wr[4], wr[5]); ra.w = bfpack2(wr[6], wr[7]);
            rb.x = bfpack2(wr[8], wr[9]); rb.y = 0u; rb.z = 0u; rb.w = 0u;
            u16* out = wab + (long long)j * 16;
            *(uint4*)(out)     = ra;
            *(uint4*)(out + 8) = rb;
        }
    }
}

// ---------------- 2. fused GEMM with att folded into K (K = 512 + 32ext) -------
// balanced XCD swizzle: XCD x handles, for every n, mt in {(x+n)&7, 8+((x+n)&7)}
// (bijective; 16-consecutive-nt grouping preserved for A-panel L2 reuse; the
//  data-dependent high-mt tiles are spread evenly across XCDs)
__global__ __launch_bounds__(256, 4) void score_gemm_kernel(
    const u16* __restrict__ Abf, const u16* __restrict__ Bbf,
    const u16* __restrict__ ftb, const u16* __restrict__ wab,
    const float* __restrict__ decp, const float* __restrict__ Ww,
    const int* __restrict__ enc_len, float* __restrict__ score_part)
{
    __shared__ __attribute__((aligned(16))) char smem[40960];
    // [0,16384) lA | [16384,32768) lB | [32768,36864) extA | [36864,40960) extB
    float* sred = (float*)smem;      // reused after final barrier

    const int bid = blockIdx.x;
    const int xcd = bid & 7;                 // physical XCD (round-robin dispatch)
    const int lcl = bid >> 3;                // 0..511 within XCD
    const int nt = lcl & 15;
    const int rr = lcl >> 4;                 // 0..31
    const int n = rr >> 1, half = rr & 1;
    const int mtl = (xcd + n) & 7;
    const int mt = half ? (8 + mtl) : mtl;

    if (mt * 128 >= enc_len[n]) return;   // fully-masked M-tile

    const int tid = threadIdx.x, wave = tid >> 6, lane = tid & 63;
    const int l16 = lane & 15, lk = lane >> 4;
    const int h = nt >> 2;

    const u16* Aptr = Abf + ((long long)n * TP + mt * 128) * ENC;
    const u16* Bptr = Bbf + (long long)nt * 128 * ENC;

    f32x4 acc[4][4];
    #pragma unroll
    for (int mi = 0; mi < 4; mi++)
        #pragma unroll
        for (int nj = 0; nj < 4; nj++) {
            f32x4 z = {0.f, 0.f, 0.f, 0.f};
            acc[mi][nj] = z;
        }

    const int wrow = (wave >> 1) * 64, wcol = (wave & 1) * 64;
    const int t0 = mt * 128, dd0 = (nt & 3) * 128;

    {
        const char* eAsrc = (const char*)(ftb + (((long long)(n * HH + h)) * TP + t0) * 16);
        const char* eBsrc = (const char*)(wab + (long long)nt * 128 * 16);
        __builtin_amdgcn_global_load_lds(
            (const AS1 void*)(eAsrc + tid * 16),
            (AS3 void*)(smem + 32768 + wave * 1024), 16, 0, 0);
        __builtin_amdgcn_global_load_lds(
            (const AS1 void*)(eBsrc + tid * 16),
            (AS3 void*)(smem + 36864 + wave * 1024), 16, 0, 0);
    }

    for (int kt = 0; kt < 8; kt++) {
        const int k0 = kt * 64;
        #pragma unroll
        for (int i = 0; i < 4; i++) {
            int b = i * 4096 + tid * 16;
            int r = b >> 7, kb = b & 127;
            int kbs = kb ^ ((r & 7) << 4);
            __builtin_amdgcn_global_load_lds(
                (const AS1 void*)(Aptr + r * ENC + k0 + (kbs >> 1)),
                (AS3 void*)(smem + i * 4096 + wave * 1024), 16, 0, 0);
            __builtin_amdgcn_global_load_lds(
                (const AS1 void*)(Bptr + r * ENC + k0 + (kbs >> 1)),
                (AS3 void*)(smem + 16384 + i * 4096 + wave * 1024), 16, 0, 0);
        }
        __syncthreads();
        #pragma unroll
        for (int ks = 0; ks < 64; ks += 32) {
            bf16x8 af[4], bf[4];
            #pragma unroll
            for (int mi = 0; mi < 4; mi++) {
                int row = wrow + mi * 16 + l16;
                int cb = (ks * 2 + lk * 16) ^ ((row & 7) << 4);
                af[mi] = *(const bf16x8*)(smem + row * 128 + cb);
            }
            #pragma unroll
            for (int nj = 0; nj < 4; nj++) {
                int row = wcol + nj * 16 + l16;
                int cb = (ks * 2 + lk * 16) ^ ((row & 7) << 4);
                bf[nj] = *(const bf16x8*)(smem + 16384 + row * 128 + cb);
            }
            #pragma unroll
            for (int mi = 0; mi < 4; mi++)
                #pragma unroll
                for (int nj = 0; nj < 4; nj++)
                    acc[mi][nj] = __builtin_amdgcn_mfma_f32_16x16x32_bf16(
                        af[mi], bf[nj], acc[mi][nj], 0, 0, 0);
        }
        __syncthreads();
    }

    // ---- K-extension step: att fold (c 0..9 valid, upper K zero) ----
    {
        const u16* eA = (const u16*)(smem + 32768);
        const u16* eB = (const u16*)(smem + 36864);
        bf16x8 zer = {0, 0, 0, 0, 0, 0, 0, 0};
        bf16x8 af[4], bf[4];
        #pragma unroll
        for (int mi = 0; mi < 4; mi++) {
            af[mi] = zer;
            if (lk < 2) af[mi] = *(const bf16x8*)(eA + (wrow + mi * 16 + l16) * 16 + lk * 8);
        }
        #pragma unroll
        for (int nj = 0; nj < 4; nj++) {
            bf[nj] = zer;
            if (lk < 2) bf[nj] = *(const bf16x8*)(eB + (wcol + nj * 16 + l16) * 16 + lk * 8);
        }
        #pragma unroll
        for (int mi = 0; mi < 4; mi++)
            #pragma unroll
            for (int nj = 0; nj < 4; nj++)
                acc[mi][nj] = __builtin_amdgcn_mfma_f32_16x16x32_bf16(
                    af[mi], bf[nj], acc[mi][nj], 0, 0, 0);
    }

    // ---- epilogue: score'= sum_d -2*ww*rcp(exp(2v)+1)  (shift cancels in softmax)
    float wm2[4], dec4[4];
    #pragma unroll
    for (int nj = 0; nj < 4; nj++) {
        int cl = wcol + nj * 16 + l16;
        wm2[nj] = -2.f * Ww[h * ATTD + dd0 + cl];
        int j = nt * 128 + cl;
        dec4[nj] = decp[((long long)0 * NB + n) * HATT + j]
                 + decp[((long long)1 * NB + n) * HATT + j]
                 + decp[((long long)2 * NB + n) * HATT + j]
                 + decp[((long long)3 * NB + n) * HATT + j];
    }

    #pragma unroll
    for (int mi = 0; mi < 4; mi++) {
        #pragma unroll
        for (int j = 0; j < 4; j++) {
            int rl = wrow + mi * 16 + lk * 4 + j;
            float s = 0.f;
            #pragma unroll
            for (int nj = 0; nj < 4; nj++) {
                float v = acc[mi][nj][j] + dec4[nj];
                float e = __expf(v + v);
                s = fmaf(wm2[nj], __builtin_amdgcn_rcpf(e + 1.f), s);
            }
            s += __shfl_xor(s, 1); s += __shfl_xor(s, 2);
            s += __shfl_xor(s, 4); s += __shfl_xor(s, 8);
            if (l16 == 0) sred[(wave & 1) * 128 + rl] = s;
        }
    }
    __syncthreads();
    if (tid < 128) {
        int t = t0 + tid;
        if (t < TT)
            score_part[((long long)((nt & 3) * NB + n) * HH + h) * SPT + t] =
                sred[tid] + sred[128 + tid];
    }
}

// ---------------- 3. masked softmax (float4 path; thread owns 8 consecutive t) -
__global__ __launch_bounds__(256) void softmax_kernel(
    const float* __restrict__ score_part, const int* __restrict__ enc_len,
    float* __restrict__ ali)
{
    int n = blockIdx.x >> 2, h = blockIdx.x & 3;
    int len = enc_len[n];
    int tid = threadIdx.x;
    int t0 = tid * 8;
    float s[8];
    #pragma unroll
    for (int i = 0; i < 8; i++) s[i] = 0.f;
    #pragma unroll
    for (int q = 0; q < 4; q++) {
        const float* rb = score_part + (((long long)(q * NB + n)) * HH + h) * SPT + t0;
        float4 a = *(const float4*)rb;
        float4 b = *(const float4*)(rb + 4);
        s[0] += a.x; s[1] += a.y; s[2] += a.z; s[3] += a.w;
        s[4] += b.x; s[5] += b.y; s[6] += b.z; s[7] += b.w;
    }
    float lmax = -3.4e38f;
    #pragma unroll
    for (int i = 0; i < 8; i++) {
        if (t0 + i < len) lmax = fmaxf(lmax, s[i]);
    }
    __shared__ float red[256];
    red[tid] = lmax; __syncthreads();
    for (int off = 128; off; off >>= 1) {
        if (tid < off) red[tid] = fmaxf(red[tid], red[tid + off]);
        __syncthreads();
    }
    float bmax = red[0];
    __syncthreads();
    float lsum = 0.f;
    #pragma unroll
    for (int i = 0; i < 8; i++) {
        if (t0 + i < len) { s[i] = expf(s[i] - bmax); lsum += s[i]; }
        else s[i] = 0.f;
    }
    red[tid] = lsum; __syncthreads();
    for (int off = 128; off; off >>= 1) {
        if (tid < off) red[tid] += red[tid + off];
        __syncthreads();
    }
    float inv = 1.f / red[0];
    float* arow = ali + ((long long)n * HH + h) * TT;
    if (t0 + 8 <= TT) {
        float4 o0 = {s[0] * inv, s[1] * inv, s[2] * inv, s[3] * inv};
        float4 o1 = {s[4] * inv, s[5] * inv, s[6] * inv, s[7] * inv};
        *(float4*)(arow + t0) = o0;
        *(float4*)(arow + t0 + 4) = o1;
    } else {
        for (int i = 0; i < 8; i++)
            if (t0 + i < TT) arow[t0 + i] = s[i] * inv;
    }
}

// ---------------- 4. a_enc partials: uint2 bf16 loads, 2 rows in flight --------
__global__ __launch_bounds__(256) void a_enc_kernel(
    const float* __restrict__ ali, const u16* __restrict__ Abf,
    const int* __restrict__ enc_len, float* __restrict__ aep)
{
    int tc = blockIdx.x & 31, n = blockIdx.x >> 5;
    int tid = threadIdx.x;
    int len = enc_len[n];
    int tbeg = tc * 63;
    int cnt = len - tbeg; if (cnt > 63) cnt = 63; if (cnt < 0) cnt = 0;
    __shared__ float aliS[HH][64];
    __shared__ float red[2][4][129];   // [tq][k][lane] transposed: conflict-free
    {
        int hh = tid >> 6, tt = tid & 63;
        aliS[hh][tt] = (tt < cnt) ? ali[((long long)n * HH + hh) * TT + tbeg + tt] : 0.f;
    }
    __syncthreads();
    const int l = tid & 127, tq = tid >> 7;   // dims 4l..4l+3; rows tl = 2*ii+tq
    float acc[HH][4];
    #pragma unroll
    for (int hh = 0; hh < HH; hh++)
        #pragma unroll
        for (int k = 0; k < 4; k++) acc[hh][k] = 0.f;
    for (int ii = 0; ii < 32; ii++) {
        int tl = ii * 2 + tq;
        if (tl < cnt) {   // explicit guard: never touch unconverted rows
            uint2 u = *(const uint2*)(Abf + ((long long)n * TP + tbeg + tl) * ENC + l * 4);
            float e0 = __builtin_bit_cast(float, u.x << 16);
            float e1 = __builtin_bit_cast(float, u.x & 0xffff0000u);
            float e2 = __builtin_bit_cast(float, u.y << 16);
            float e3 = __builtin_bit_cast(float, u.y & 0xffff0000u);
            #pragma unroll
            for (int hh = 0; hh < HH; hh++) {
                float w = aliS[hh][tl];
                acc[hh][0] += w * e0; acc[hh][1] += w * e1;
                acc[hh][2] += w * e2; acc[hh][3] += w * e3;
            }
        }
    }
    #pragma unroll
    for (int hh = 0; hh < HH; hh++) {
        __syncthreads();
        #pragma unroll
        for (int k = 0; k < 4; k++) red[tq][k][l] = acc[hh][k];
        __syncthreads();
        int d2 = tid * 2;
        float v0 = red[0][d2 & 3][d2 >> 2] + red[1][d2 & 3][d2 >> 2];
        int d3 = d2 + 1;
        float v1 = red[0][d3 & 3][d3 >> 2] + red[1][d3 & 3][d3 >> 2];
        float2 o = {v0, v1};
        *(float2*)(aep + (((long long)tc * NB + n) * HH + hh) * ENC + d2) = o;
    }
}

// ---------------- 5. ctx_tmp partials (K-split 8, grid 64) ---------------------
__global__ __launch_bounds__(256) void ctx_tmp_kernel(
    const float* __restrict__ aep, const float* __restrict__ We,
    const float* __restrict__ be, float* __restrict__ ctmp)
{
    int kc = blockIdx.x >> 3, jc = blockIdx.x & 7;   // kc 0..7 (64-K), jc 0..7
    int tid = threadIdx.x;
    int j = jc * 256 + tid;
    int h = j >> 9;                       // uniform per block
    __shared__ float aes[16 * 64];
    for (int i = tid; i < 1024; i += 256) {
        int nn = i >> 6, kk = i & 63;
        float s = 0.f;
        for (int tc = 0; tc < 32; tc++)
            s += aep[(((long long)tc * NB + nn) * HH + h) * ENC + kc * 64 + kk];
        aes[i] = s;
    }
    __syncthreads();
    float acc[NB];
    #pragma unroll
    for (int n = 0; n < NB; n++) acc[n] = 0.f;
    const float4* w4 = (const float4*)(We + (long long)j * 512 + kc * 64);
    for (int e4 = 0; e4 < 16; e4++) {
        float4 w = w4[e4];
        #pragma unroll
        for (int n = 0; n < NB; n++) {
            const float* a = aes + n * 64 + e4 * 4;
            acc[n] += w.x * a[0] + w.y * a[1] + w.z * a[2] + w.w * a[3];
        }
    }
    float bias = (kc == 0) ? be[j] : 0.f;
    #pragma unroll
    for (int n = 0; n < NB; n++)
        ctmp[((long long)kc * NB + n) * HATT + j] = acc[n] + bias;
}

// ---------------- 6. ctx_out (grid 32 = 16 ec x 2 nc) --------------------------
__global__ __launch_bounds__(256) void ctx_out_kernel(
    const float* __restrict__ ctmp, const float* __restrict__ Wc,
    const float* __restrict__ bc, float* __restrict__ out_ctx)
{
    int ec = blockIdx.x & 15, nc = blockIdx.x >> 4;
    int tid = threadIdx.x;
    __shared__ float ct[8 * 2048];        // 64 KB: ct[nn][j]
    __shared__ float red[8][8][33];       // [kq][nn][eo+pad]: conflict-free
    for (int i = tid; i < 8 * 2048; i += 256) {
        int nn = i >> 11, j = i & 2047;
        int n = nc * 8 + nn;
        float s = 0.f;
        #pragma unroll
        for (int kc = 0; kc < 8; kc++)
            s += ctmp[((long long)kc * NB + n) * HATT + j];
        ct[i] = s;
    }
    __syncthreads();
    int eo = tid & 31, kq = tid >> 5;     // 32 eo x 8 K-slices (256 j each)
    int eg = ec * 32 + eo;
    float acc[8];
    #pragma unroll
    for (int nn = 0; nn < 8; nn++) acc[nn] = 0.f;
    const float4* w4 = (const float4*)(Wc + (long long)eg * HATT + kq * 256);
    for (int j4 = 0; j4 < 64; j4++) {
        float4 w = w4[j4];
        #pragma unroll
        for (int nn = 0; nn < 8; nn++) {
            const float* a = ct + nn * 2048 + kq * 256 + j4 * 4;
            acc[nn] += w.x * a[0] + w.y * a[1] + w.z * a[2] + w.w * a[3];
        }
    }
    #pragma unroll
    for (int nn = 0; nn < 8; nn++) red[kq][nn][eo] = acc[nn];
    __syncthreads();
    {
        int eo2 = tid & 31, nn2 = tid >> 5;   // 256 threads = 32 eo x 8 nn
        float s = 0.f;
        #pragma unroll
        for (int kq2 = 0; kq2 < 8; kq2++) s += red[kq2][nn2][eo2];
        out_ctx[((long long)(nc * 8 + nn2)) * 512 + ec * 32 + eo2] = s + bc[ec * 32 + eo2];
    }
}

// ---------------- launch ----------------
extern "C" void kernel_launch(void* const* d_in, const int* in_sizes, int n_in,
                              void* d_out, int out_size, void* d_ws, size_t ws_size,
                              hipStream_t stream)
{
    (void)in_sizes; (void)n_in; (void)out_size; (void)ws_size;
    const float* enc_pad  = (const float*)d_in[0];
    const int*   enc_len  = (const int*)  d_in[1];
    const float* dec_prev = (const float*)d_in[2];
    const float* ali_prev = (const float*)d_in[3];
    const float* We = (const float*)d_in[4];
    const float* be = (const float*)d_in[5];
    const float* Wk = (const float*)d_in[6];
    const float* Wd = (const float*)d_in[7];
    const float* WF = (const float*)d_in[8];
    const float* bF = (const float*)d_in[9];
    const float* Wa = (const float*)d_in[10];
    const float* Ww = (const float*)d_in[11];
    const float* Wc = (const float*)d_in[12];
    const float* bc = (const float*)d_in[13];

    char* ws = (char*)d_ws;
    u16*   Abf  = (u16*)  (ws);                 // 33,554,432 B
    u16*   Wkbf = (u16*)  (ws + 33554432);      //  2,097,152 B
    u16*   ftb  = (u16*)  (ws + 35651584);      //  4,194,304 B  [n*h][2048][16]
    u16*   wab  = (u16*)  (ws + 39845888);      //     65,536 B  [2048][16]
    float* decp = (float*)(ws + 39911424);      //    524,288 B  [4][16][2048]
    float* spart= (float*)(ws + 40435712);      //  2,097,152 B  [4][16][4][2048]
    float* aep  = (float*)(ws + 40435712);      // alias spart (dead after softmax)
    float* ctmp = (float*)(ws + 35651584);      // alias ftb (dead after gemm)
    // high-water 44,630,016 B (same proven envelope as rounds 5-8)

    float* ali = (float*)d_out;                 // [16][4][2000]
    float* ctx = (float*)d_out + NB * HH * TT;  // [16][512]

    prep_kernel      <<<8996, 256, 0, stream>>>(enc_pad, Wk, ali_prev, WF, bF,
                                                dec_prev, Wd, Wa, enc_len,
                                                Abf, Wkbf, ftb, wab, decp);
    score_gemm_kernel<<<4096, 256, 0, stream>>>(Abf, Wkbf, ftb, wab, decp, Ww,
                                                enc_len, spart);
    softmax_kernel   <<<64,   256, 0, stream>>>(spart, enc_len, ali);
    a_enc_kernel     <<<512,  256, 0, stream>>>(ali, Abf, enc_len, aep);
    ctx_tmp_kernel   <<<64,   256, 0, stream>>>(aep, We, be, ctmp);
    ctx_out_kernel   <<<32,   256, 0, stream>>>(ctmp, Wc, bc, ctx);
}